// Round 1
// baseline (5126.971 us; speedup 1.0000x reference)
//
#include <hip/hip_runtime.h>
#include <math.h>

// Problem constants
constexpr int B  = 32;
constexpr int T  = 24;
constexpr int D  = 13;
constexpr int N  = 1024;   // 32*32 spatial
constexpr int SZ = B * D * N;            // one [B,13,32,32] state tensor (425984 floats)
constexpr int GSZ = B * 52 * N;          // gates buffer

__device__ __forceinline__ float sigmoidf_(float x) { return 1.f / (1.f + __expf(-x)); }

// ---------------------------------------------------------------- zero init
__global__ void k_zero(float* __restrict__ p, int n) {
    int i = blockIdx.x * 256 + threadIdx.x;
    if (i < n) p[i] = 0.f;
}

// ---------------------------------------------------------------- 3x3 gate conv
// grid: (4 row-tiles, 32 batch, 4 co-splits), block 256 (32x8 pixels)
// gates[b][co][pix] = conv3x3(concat([xt, h]))[co], co split 13 per block.z
__global__ __launch_bounds__(256) void k_conv(
    const float* __restrict__ x1, const float* __restrict__ Wg,
    const float* __restrict__ h, float* __restrict__ gates, int t)
{
    __shared__ __align__(16) float s_w[26 * 9 * 16];  // [ci][tap][co16 (13 used)]
    const int tile = blockIdx.x, b = blockIdx.y, z = blockIdx.z;
    const int tid = threadIdx.x;

    for (int idx = tid; idx < 26 * 9 * 16; idx += 256) {
        int cl = idx & 15; int r = idx >> 4; int tap = r % 9; int ci = r / 9;
        float w = 0.f;
        if (cl < 13) w = Wg[((z * 13 + cl) * 26 + ci) * 9 + tap];
        s_w[idx] = w;
    }
    __syncthreads();

    const int x = tid & 31, ry = tid >> 5;
    const int y = tile * 8 + ry;
    const float* xt = x1 + ((size_t)b * T + t) * D * N;
    const float* hb = h + (size_t)b * D * N;

    float acc[16];
#pragma unroll
    for (int i = 0; i < 16; ++i) acc[i] = 0.f;

    for (int ci = 0; ci < 26; ++ci) {
        const float* src = (ci < 13) ? (xt + ci * N) : (hb + (ci - 13) * N);
        float tv[9];
#pragma unroll
        for (int ky = 0; ky < 3; ++ky) {
            const int gy = y + ky - 1;
            const bool oky = (unsigned)gy < 32u;
#pragma unroll
            for (int kx = 0; kx < 3; ++kx) {
                const int gx = x + kx - 1;
                tv[ky * 3 + kx] = (oky && (unsigned)gx < 32u) ? src[gy * 32 + gx] : 0.f;
            }
        }
        const float4* wr = (const float4*)&s_w[ci * 9 * 16];
#pragma unroll
        for (int tap = 0; tap < 9; ++tap) {
            const float v = tv[tap];
#pragma unroll
            for (int c4 = 0; c4 < 4; ++c4) {
                float4 w4 = wr[tap * 4 + c4];
                acc[c4 * 4 + 0] += v * w4.x;
                acc[c4 * 4 + 1] += v * w4.y;
                acc[c4 * 4 + 2] += v * w4.z;
                acc[c4 * 4 + 3] += v * w4.w;
            }
        }
    }
    const int pix = y * 32 + x;
    float* gb = gates + (size_t)b * 52 * N + (size_t)z * 13 * N + pix;
#pragma unroll
    for (int cl = 0; cl < 13; ++cl) gb[cl * N] = acc[cl];
}

// ---------------------------------------------------------------- LSTM pointwise + K/V projections
// one thread per (b, pixel); 128 blocks x 256
__global__ __launch_bounds__(256) void k_point(
    const float* __restrict__ gates, float* __restrict__ c, const float* __restrict__ m,
    float* __restrict__ h_tmp, float* __restrict__ kh, float* __restrict__ vh,
    float* __restrict__ km, float* __restrict__ vm,
    const float* __restrict__ Wkh, const float* __restrict__ Wvh,
    const float* __restrict__ Wkm, const float* __restrict__ Wvm)
{
    const int i = blockIdx.x * 256 + threadIdx.x;     // < B*N exactly
    const int b = i >> 10, pix = i & 1023;
    const size_t gb = (size_t)b * 52 * N + pix;
    const size_t bb = (size_t)b * D * N + pix;

    float ht[13], mv[13];
#pragma unroll
    for (int d = 0; d < 13; ++d) {
        float ig = sigmoidf_(gates[gb + (size_t)d * N]);
        float fg = sigmoidf_(gates[gb + (size_t)(13 + d) * N]);
        float gg = tanhf(gates[gb + (size_t)(26 + d) * N]);
        float og = sigmoidf_(gates[gb + (size_t)(39 + d) * N]);
        float cn = fg * c[bb + (size_t)d * N] + ig * gg;
        c[bb + (size_t)d * N] = cn;
        float hv = og * tanhf(cn);
        ht[d] = hv;
        h_tmp[bb + (size_t)d * N] = hv;
        mv[d] = m[bb + (size_t)d * N];
    }
#pragma unroll
    for (int d = 0; d < 13; ++d) {
        float akh = 0.f, avh = 0.f, akm = 0.f, avm = 0.f;
#pragma unroll
        for (int j = 0; j < 13; ++j) {
            akh += Wkh[d * 13 + j] * ht[j];
            avh += Wvh[d * 13 + j] * ht[j];
            akm += Wkm[d * 13 + j] * mv[j];
            avm += Wvm[d * 13 + j] * mv[j];
        }
        kh[bb + (size_t)d * N] = akh;
        vh[bb + (size_t)d * N] = avh;
        km[bb + (size_t)d * N] = akm;
        vm[bb + (size_t)d * N] = avm;
    }
}

// ---------------------------------------------------------------- fused dual attention + SAM epilogue
// grid (16 query-tiles, 32 batch), block 256. 64 queries/block, both branches.
// thread: 2 queries x 1/8 of keys, single-pass exp accumulation (scores are
// provably small: |s| <= sum|q||k| << 88, so no max-subtraction needed).
__global__ __launch_bounds__(256) void k_attn(
    const float* __restrict__ kh, const float* __restrict__ vh,
    const float* __restrict__ km, const float* __restrict__ vm,
    const float* __restrict__ h_tmp,
    const float* __restrict__ Wq, const float* __restrict__ Wz, const float* __restrict__ Wm,
    float* __restrict__ m, float* __restrict__ h)
{
    __shared__ __align__(16) float s_kv[4 * 13 * 64];  // [arr][d][j]
    __shared__ __align__(16) float s_hf[13 * 64];
    __shared__ float s_zh[13 * 64], s_zm[13 * 64], s_z[13 * 64];

    const int b = blockIdx.y;
    const int n0 = blockIdx.x * 64;
    const int tid = threadIdx.x;
    const size_t bb = (size_t)b * D * N;

    for (int idx = tid; idx < 832; idx += 256)
        s_hf[idx] = h_tmp[bb + (size_t)(idx >> 6) * N + n0 + (idx & 63)];
    __syncthreads();

    const int e8 = tid & 7, qp = tid >> 3;   // qp in 0..31
    const int q0 = 2 * qp, q1 = q0 + 1;

    // q = Wq * hf for this thread's two queries
    float qr0[13], qr1[13];
#pragma unroll
    for (int d = 0; d < 13; ++d) {
        float a0 = 0.f, a1 = 0.f;
#pragma unroll
        for (int j = 0; j < 13; ++j) {
            float w = Wq[d * 13 + j];
            a0 += w * s_hf[j * 64 + q0];
            a1 += w * s_hf[j * 64 + q1];
        }
        qr0[d] = a0; qr1[d] = a1;
    }

    float dh0 = 0.f, dh1 = 0.f, dm0 = 0.f, dm1 = 0.f;
    float nh0[13], nh1[13], nm0[13], nm1[13];
#pragma unroll
    for (int d = 0; d < 13; ++d) { nh0[d] = nh1[d] = nm0[d] = nm1[d] = 0.f; }

    for (int cc = 0; cc < 16; ++cc) {
        __syncthreads();
        for (int idx = tid; idx < 3328; idx += 256) {
            int a = idx / 832; int rem = idx - a * 832; int d = rem >> 6; int j = rem & 63;
            const float* s = (a == 0) ? kh : (a == 1) ? vh : (a == 2) ? km : vm;
            s_kv[idx] = s[bb + (size_t)d * N + cc * 64 + j];
        }
        __syncthreads();
#pragma unroll
        for (int g = 0; g < 2; ++g) {
            const int j0 = e8 * 8 + g * 4;
            // ---- h branch ----
            {
                float4 sa = {0, 0, 0, 0}, sb = {0, 0, 0, 0};
#pragma unroll
                for (int d = 0; d < 13; ++d) {
                    float4 k4 = *(const float4*)&s_kv[0 * 832 + d * 64 + j0];
                    float a0 = qr0[d], a1 = qr1[d];
                    sa.x += a0 * k4.x; sa.y += a0 * k4.y; sa.z += a0 * k4.z; sa.w += a0 * k4.w;
                    sb.x += a1 * k4.x; sb.y += a1 * k4.y; sb.z += a1 * k4.z; sb.w += a1 * k4.w;
                }
                float ea0 = __expf(sa.x), ea1 = __expf(sa.y), ea2 = __expf(sa.z), ea3 = __expf(sa.w);
                float eb0 = __expf(sb.x), eb1 = __expf(sb.y), eb2 = __expf(sb.z), eb3 = __expf(sb.w);
                dh0 += (ea0 + ea1) + (ea2 + ea3);
                dh1 += (eb0 + eb1) + (eb2 + eb3);
#pragma unroll
                for (int d = 0; d < 13; ++d) {
                    float4 v4 = *(const float4*)&s_kv[1 * 832 + d * 64 + j0];
                    nh0[d] += ea0 * v4.x + ea1 * v4.y + ea2 * v4.z + ea3 * v4.w;
                    nh1[d] += eb0 * v4.x + eb1 * v4.y + eb2 * v4.z + eb3 * v4.w;
                }
            }
            // ---- m branch ----
            {
                float4 sa = {0, 0, 0, 0}, sb = {0, 0, 0, 0};
#pragma unroll
                for (int d = 0; d < 13; ++d) {
                    float4 k4 = *(const float4*)&s_kv[2 * 832 + d * 64 + j0];
                    float a0 = qr0[d], a1 = qr1[d];
                    sa.x += a0 * k4.x; sa.y += a0 * k4.y; sa.z += a0 * k4.z; sa.w += a0 * k4.w;
                    sb.x += a1 * k4.x; sb.y += a1 * k4.y; sb.z += a1 * k4.z; sb.w += a1 * k4.w;
                }
                float ea0 = __expf(sa.x), ea1 = __expf(sa.y), ea2 = __expf(sa.z), ea3 = __expf(sa.w);
                float eb0 = __expf(sb.x), eb1 = __expf(sb.y), eb2 = __expf(sb.z), eb3 = __expf(sb.w);
                dm0 += (ea0 + ea1) + (ea2 + ea3);
                dm1 += (eb0 + eb1) + (eb2 + eb3);
#pragma unroll
                for (int d = 0; d < 13; ++d) {
                    float4 v4 = *(const float4*)&s_kv[3 * 832 + d * 64 + j0];
                    nm0[d] += ea0 * v4.x + ea1 * v4.y + ea2 * v4.z + ea3 * v4.w;
                    nm1[d] += eb0 * v4.x + eb1 * v4.y + eb2 * v4.z + eb3 * v4.w;
                }
            }
        }
    }

    // reduce the 8 key-partitions (contiguous 8-lane groups)
#pragma unroll
    for (int s = 1; s < 8; s <<= 1) {
        dh0 += __shfl_xor(dh0, s, 8); dh1 += __shfl_xor(dh1, s, 8);
        dm0 += __shfl_xor(dm0, s, 8); dm1 += __shfl_xor(dm1, s, 8);
#pragma unroll
        for (int d = 0; d < 13; ++d) {
            nh0[d] += __shfl_xor(nh0[d], s, 8);
            nh1[d] += __shfl_xor(nh1[d], s, 8);
            nm0[d] += __shfl_xor(nm0[d], s, 8);
            nm1[d] += __shfl_xor(nm1[d], s, 8);
        }
    }
    if (e8 == 0) {
        float r0 = 1.f / dh0, r1 = 1.f / dh1, t0 = 1.f / dm0, t1 = 1.f / dm1;
#pragma unroll
        for (int d = 0; d < 13; ++d) {
            s_zh[d * 64 + q0] = nh0[d] * r0; s_zh[d * 64 + q1] = nh1[d] * r1;
            s_zm[d * 64 + q0] = nm0[d] * t0; s_zm[d * 64 + q1] = nm1[d] * t1;
        }
    }
    __syncthreads();

    // Z = Wz * [Zh; Zm]
    for (int idx = tid; idx < 832; idx += 256) {
        int d = idx >> 6, j = idx & 63;
        float a = 0.f;
#pragma unroll
        for (int ci = 0; ci < 13; ++ci) a += Wz[d * 26 + ci] * s_zh[ci * 64 + j];
#pragma unroll
        for (int ci = 0; ci < 13; ++ci) a += Wz[d * 26 + 13 + ci] * s_zm[ci * 64 + j];
        s_z[idx] = a;
    }
    __syncthreads();

    // comb = Wm * [Z; hf]; state update
    for (int idx = tid; idx < 832; idx += 256) {
        int d = idx >> 6, j = idx & 63;
        float mo = 0.f, mg = 0.f, mi = 0.f;
#pragma unroll
        for (int ci = 0; ci < 13; ++ci) {
            float zc = s_z[ci * 64 + j];
            mo += Wm[d * 26 + ci] * zc;
            mg += Wm[(13 + d) * 26 + ci] * zc;
            mi += Wm[(26 + d) * 26 + ci] * zc;
        }
#pragma unroll
        for (int ci = 0; ci < 13; ++ci) {
            float hc = s_hf[ci * 64 + j];
            mo += Wm[d * 26 + 13 + ci] * hc;
            mg += Wm[(13 + d) * 26 + 13 + ci] * hc;
            mi += Wm[(26 + d) * 26 + 13 + ci] * hc;
        }
        mi = sigmoidf_(mi);
        const size_t gi = bb + (size_t)d * N + n0 + j;
        float mn = (1.f - mi) * m[gi] + mi * tanhf(mg);
        m[gi] = mn;
        h[gi] = sigmoidf_(mo) * mn;
    }
}

// ---------------------------------------------------------------- final 1x1 conv + log_softmax
__global__ __launch_bounds__(256) void k_final(
    const float* __restrict__ c, const float* __restrict__ Wf,
    const float* __restrict__ bf, float* __restrict__ out)
{
    const int i = blockIdx.x * 256 + threadIdx.x;   // < B*N exactly
    const int b = i >> 10, pix = i & 1023;
    const size_t base = (size_t)b * D * N + pix;
    float cv[13];
#pragma unroll
    for (int d = 0; d < 13; ++d) cv[d] = c[base + (size_t)d * N];
    float lg[8]; float mx = -1e30f;
#pragma unroll
    for (int k = 0; k < 8; ++k) {
        float a = bf[k];
#pragma unroll
        for (int d = 0; d < 13; ++d) a += Wf[k * 13 + d] * cv[d];
        lg[k] = a; mx = fmaxf(mx, a);
    }
    float s = 0.f;
#pragma unroll
    for (int k = 0; k < 8; ++k) s += __expf(lg[k] - mx);
    float lse = mx + logf(s);
    const size_t ob = (size_t)b * 8 * N + pix;
#pragma unroll
    for (int k = 0; k < 8; ++k) out[ob + (size_t)k * N] = lg[k] - lse;
}

// ---------------------------------------------------------------- host launcher
extern "C" void kernel_launch(void* const* d_in, const int* in_sizes, int n_in,
                              void* d_out, int out_size, void* d_ws, size_t ws_size,
                              hipStream_t stream) {
    const float* x1  = (const float*)d_in[0];
    const float* Wg  = (const float*)d_in[1];
    const float* Wq  = (const float*)d_in[2];
    const float* Wkh = (const float*)d_in[3];
    const float* Wvh = (const float*)d_in[4];
    const float* Wkm = (const float*)d_in[5];
    const float* Wvm = (const float*)d_in[6];
    const float* Wz  = (const float*)d_in[7];
    const float* Wm  = (const float*)d_in[8];
    const float* Wf  = (const float*)d_in[9];
    const float* bf  = (const float*)d_in[10];

    float* ws    = (float*)d_ws;            // needs 12*SZ*4 = ~20.5 MB
    float* c     = ws;
    float* h     = ws + (size_t)SZ;
    float* m     = ws + (size_t)2 * SZ;
    float* h_tmp = ws + (size_t)3 * SZ;
    float* kh    = ws + (size_t)4 * SZ;
    float* vh    = ws + (size_t)5 * SZ;
    float* km    = ws + (size_t)6 * SZ;
    float* vm    = ws + (size_t)7 * SZ;
    float* gates = ws + (size_t)8 * SZ;     // 4*SZ floats

    // zero c, h, m (contiguous 3*SZ)
    k_zero<<<(3 * SZ + 255) / 256, 256, 0, stream>>>(ws, 3 * SZ);

    for (int t = 0; t < T; ++t) {
        k_conv<<<dim3(4, 32, 4), 256, 0, stream>>>(x1, Wg, h, gates, t);
        k_point<<<(B * N) / 256, 256, 0, stream>>>(gates, c, m, h_tmp, kh, vh, km, vm,
                                                   Wkh, Wvh, Wkm, Wvm);
        k_attn<<<dim3(16, 32), 256, 0, stream>>>(kh, vh, km, vm, h_tmp, Wq, Wz, Wm, m, h);
    }
    k_final<<<(B * N) / 256, 256, 0, stream>>>(c, Wf, bf, (float*)d_out);
}

// Round 2
// 2038.380 us; speedup vs baseline: 2.5152x; 2.5152x over previous
//
#include <hip/hip_runtime.h>
#include <math.h>

// Problem constants
constexpr int B  = 32;
constexpr int T  = 24;
constexpr int D  = 13;
constexpr int N  = 1024;   // 32*32 spatial
constexpr int SZ = B * D * N;

typedef __attribute__((ext_vector_type(8))) short bf16x8;
typedef __attribute__((ext_vector_type(4))) float f32x4;

__device__ __forceinline__ float sigmoidf_(float x) { return 1.f / (1.f + __expf(-x)); }

__device__ __forceinline__ unsigned short f2bf(float f) {
    unsigned u = __float_as_uint(f);
    u += 0x7FFF + ((u >> 16) & 1);          // round-to-nearest-even
    return (unsigned short)(u >> 16);
}

// ---------------------------------------------------------------- zero init
__global__ void k_zero(float* __restrict__ p, int n) {
    int i = blockIdx.x * 256 + threadIdx.x;
    if (i < n) p[i] = 0.f;
}

// ---------------------------------------------------------------- 3x3 gate conv (unchanged)
__global__ __launch_bounds__(256) void k_conv(
    const float* __restrict__ x1, const float* __restrict__ Wg,
    const float* __restrict__ h, float* __restrict__ gates, int t)
{
    __shared__ __align__(16) float s_w[26 * 9 * 16];
    const int tile = blockIdx.x, b = blockIdx.y, z = blockIdx.z;
    const int tid = threadIdx.x;

    for (int idx = tid; idx < 26 * 9 * 16; idx += 256) {
        int cl = idx & 15; int r = idx >> 4; int tap = r % 9; int ci = r / 9;
        float w = 0.f;
        if (cl < 13) w = Wg[((z * 13 + cl) * 26 + ci) * 9 + tap];
        s_w[idx] = w;
    }
    __syncthreads();

    const int x = tid & 31, ry = tid >> 5;
    const int y = tile * 8 + ry;
    const float* xt = x1 + ((size_t)b * T + t) * D * N;
    const float* hb = h + (size_t)b * D * N;

    float acc[16];
#pragma unroll
    for (int i = 0; i < 16; ++i) acc[i] = 0.f;

    for (int ci = 0; ci < 26; ++ci) {
        const float* src = (ci < 13) ? (xt + ci * N) : (hb + (ci - 13) * N);
        float tv[9];
#pragma unroll
        for (int ky = 0; ky < 3; ++ky) {
            const int gy = y + ky - 1;
            const bool oky = (unsigned)gy < 32u;
#pragma unroll
            for (int kx = 0; kx < 3; ++kx) {
                const int gx = x + kx - 1;
                tv[ky * 3 + kx] = (oky && (unsigned)gx < 32u) ? src[gy * 32 + gx] : 0.f;
            }
        }
        const float4* wr = (const float4*)&s_w[ci * 9 * 16];
#pragma unroll
        for (int tap = 0; tap < 9; ++tap) {
            const float v = tv[tap];
#pragma unroll
            for (int c4 = 0; c4 < 4; ++c4) {
                float4 w4 = wr[tap * 4 + c4];
                acc[c4 * 4 + 0] += v * w4.x;
                acc[c4 * 4 + 1] += v * w4.y;
                acc[c4 * 4 + 2] += v * w4.z;
                acc[c4 * 4 + 3] += v * w4.w;
            }
        }
    }
    const int pix = y * 32 + x;
    float* gb = gates + (size_t)b * 52 * N + (size_t)z * 13 * N + pix;
#pragma unroll
    for (int cl = 0; cl < 13; ++cl) gb[cl * N] = acc[cl];
}

// ---------------------------------------------------------------- LSTM pointwise + Q/K/V projections (bf16 out)
__global__ __launch_bounds__(256) void k_point(
    const float* __restrict__ gates, float* __restrict__ c, const float* __restrict__ m,
    float* __restrict__ h_tmp,
    unsigned short* __restrict__ qT, unsigned short* __restrict__ khT,
    unsigned short* __restrict__ kmT, unsigned short* __restrict__ vh,
    unsigned short* __restrict__ vm,
    const float* __restrict__ Wq, const float* __restrict__ Wkh, const float* __restrict__ Wvh,
    const float* __restrict__ Wkm, const float* __restrict__ Wvm)
{
    const int i = blockIdx.x * 256 + threadIdx.x;     // < B*N
    const int b = i >> 10, pix = i & 1023;
    const size_t gb = (size_t)b * 52 * N + pix;
    const size_t bb = (size_t)b * D * N + pix;

    float ht[13], mv[13];
#pragma unroll
    for (int d = 0; d < 13; ++d) {
        float ig = sigmoidf_(gates[gb + (size_t)d * N]);
        float fg = sigmoidf_(gates[gb + (size_t)(13 + d) * N]);
        float gg = tanhf(gates[gb + (size_t)(26 + d) * N]);
        float og = sigmoidf_(gates[gb + (size_t)(39 + d) * N]);
        float cn = fg * c[bb + (size_t)d * N] + ig * gg;
        c[bb + (size_t)d * N] = cn;
        float hv = og * tanhf(cn);
        ht[d] = hv;
        h_tmp[bb + (size_t)d * N] = hv;
        mv[d] = m[bb + (size_t)d * N];
    }
    unsigned short qb[16], khb[16], kmb[16];
#pragma unroll
    for (int d = 0; d < 13; ++d) {
        float aq = 0.f, akh = 0.f, avh = 0.f, akm = 0.f, avm = 0.f;
#pragma unroll
        for (int j = 0; j < 13; ++j) {
            aq  += Wq [d * 13 + j] * ht[j];
            akh += Wkh[d * 13 + j] * ht[j];
            avh += Wvh[d * 13 + j] * ht[j];
            akm += Wkm[d * 13 + j] * mv[j];
            avm += Wvm[d * 13 + j] * mv[j];
        }
        qb[d]  = f2bf(aq);
        khb[d] = f2bf(akh);
        kmb[d] = f2bf(akm);
        vh[bb + (size_t)d * N] = f2bf(avh);
        vm[bb + (size_t)d * N] = f2bf(avm);
    }
#pragma unroll
    for (int d = 13; d < 16; ++d) { qb[d] = 0; khb[d] = 0; kmb[d] = 0; }
    const size_t ro = (size_t)i * 16;
    ((uint4*)(qT  + ro))[0] = ((const uint4*)qb)[0];
    ((uint4*)(qT  + ro))[1] = ((const uint4*)qb)[1];
    ((uint4*)(khT + ro))[0] = ((const uint4*)khb)[0];
    ((uint4*)(khT + ro))[1] = ((const uint4*)khb)[1];
    ((uint4*)(kmT + ro))[0] = ((const uint4*)kmb)[0];
    ((uint4*)(kmT + ro))[1] = ((const uint4*)kmb)[1];
}

// ---------------------------------------------------------------- MFMA dual attention + fused SAM epilogue
// grid (32 qtiles, 32 batch), block 256 = 4 waves.
// wave w: branch = w>>1 (0:h, 1:m), queries (w&1)*16 .. +16 of this 32-query tile.
// S-tile computed transposed (A=K,B=q) so exp(S) lands directly in the PV B-operand layout.
__global__ __launch_bounds__(256) void k_attn(
    const unsigned short* __restrict__ qT, const unsigned short* __restrict__ khT,
    const unsigned short* __restrict__ kmT, const unsigned short* __restrict__ vh,
    const unsigned short* __restrict__ vm, const float* __restrict__ h_tmp,
    const float* __restrict__ Wz, const float* __restrict__ Wm,
    float* __restrict__ m, float* __restrict__ h)
{
    __shared__ __align__(16) unsigned short s_k[2][64 * 24]; // [br][key*24 + d], 16 d used, 8 pad
    __shared__ __align__(16) unsigned short s_v[2][16 * 72]; // [br][d*72 + key], rows 13..15 zero
    __shared__ float s_hf[13 * 33];
    __shared__ float s_zh[13 * 33], s_zm[13 * 33], s_zc[13 * 33];
    __shared__ float s_wz[13 * 26];
    __shared__ float s_wm[39 * 26];

    const int b = blockIdx.y, n0 = blockIdx.x * 32, tid = threadIdx.x;
    const int lane = tid & 63, w = tid >> 6;
    const int g = lane >> 4, l15 = lane & 15;
    const int br = w >> 1;
    const size_t bbN = (size_t)b * D * N;

    // stage weights, hf, zero V pad rows
    for (int idx = tid; idx < 13 * 26; idx += 256) s_wz[idx] = Wz[idx];
    for (int idx = tid; idx < 39 * 26; idx += 256) s_wm[idx] = Wm[idx];
    for (int idx = tid; idx < 13 * 32; idx += 256) {
        int d = idx >> 5, p = idx & 31;
        s_hf[d * 33 + p] = h_tmp[bbN + (size_t)d * N + n0 + p];
    }
    for (int idx = tid; idx < 2 * 3 * 72; idx += 256) {
        int br2 = idx / 216, rem = idx % 216;
        s_v[br2][13 * 72 + rem] = 0;
    }

    // constant q fragment (B operand): B1[k=d][n=query], k=8g+j; g>=2 -> zero (d>=16 pad)
    bf16x8 b1 = {0, 0, 0, 0, 0, 0, 0, 0};
    if (g < 2) {
        const unsigned short* qp = qT + ((size_t)b * N + n0 + (w & 1) * 16 + l15) * 16 + 8 * g;
        b1 = *(const bf16x8*)qp;
    }

    f32x4 zacc = {0.f, 0.f, 0.f, 0.f};
    float den = 0.f;

    for (int cc = 0; cc < 16; ++cc) {
        __syncthreads();
        {   // stage K (both branches): 2*64 rows x 32B = 256 x 16B pieces
            int br2 = tid >> 7, row = (tid >> 1) & 63, part = tid & 1;
            const unsigned short* src = (br2 ? kmT : khT)
                + ((size_t)b * N + cc * 64 + row) * 16 + part * 8;
            *(uint4*)&s_k[br2][row * 24 + part * 8] = *(const uint4*)src;
        }
        if (tid < 208) {  // stage V: 2*13 rows x 128B = 208 x 16B pieces
            int br2 = tid >= 104;
            int rem = tid - 104 * br2;
            int d = rem >> 3, part = rem & 7;
            const unsigned short* src = (br2 ? vm : vh)
                + bbN + (size_t)d * N + cc * 64 + part * 8;
            *(uint4*)&s_v[br2][d * 72 + part * 8] = *(const uint4*)src;
        }
        __syncthreads();

#pragma unroll
        for (int u = 0; u < 2; ++u) {
            // two S-tiles (keys permuted so PV B-frag is reg-direct)
            bf16x8 a0 = {0, 0, 0, 0, 0, 0, 0, 0}, a1v = {0, 0, 0, 0, 0, 0, 0, 0};
            if (g < 2) {
                const int rbase = 32 * u + 8 * (l15 >> 2) + (l15 & 3);
                a0  = *(const bf16x8*)&s_k[br][(rbase)     * 24 + 8 * g];
                a1v = *(const bf16x8*)&s_k[br][(rbase + 4) * 24 + 8 * g];
            }
            f32x4 d0 = {0.f, 0.f, 0.f, 0.f}, d1 = {0.f, 0.f, 0.f, 0.f};
            d0 = __builtin_amdgcn_mfma_f32_16x16x32_bf16(a0,  b1, d0, 0, 0, 0);
            d1 = __builtin_amdgcn_mfma_f32_16x16x32_bf16(a1v, b1, d1, 0, 0, 0);

            float e0[4], e1[4];
#pragma unroll
            for (int r = 0; r < 4; ++r) { e0[r] = __expf(d0[r]); e1[r] = __expf(d1[r]); }
            den += ((e0[0] + e0[1]) + (e0[2] + e0[3])) + ((e1[0] + e1[1]) + (e1[2] + e1[3]));

            bf16x8 b2;
#pragma unroll
            for (int r = 0; r < 4; ++r) {
                b2[r]     = (short)f2bf(e0[r]);
                b2[r + 4] = (short)f2bf(e1[r]);
            }
            // V fragment: A2[m=d][k=key], keys 32u+8g..+7
            bf16x8 a2 = *(const bf16x8*)&s_v[br][l15 * 72 + 32 * u + 8 * g];
            zacc = __builtin_amdgcn_mfma_f32_16x16x32_bf16(a2, b2, zacc, 0, 0, 0);
        }
    }

    // denominator: reduce over the 4 key-partitions (lane bits 4,5)
    den += __shfl_xor(den, 16, 64);
    den += __shfl_xor(den, 32, 64);
    const float rd = 1.f / den;

    float* zs = br ? s_zm : s_zh;
    const int q = (w & 1) * 16 + l15;
#pragma unroll
    for (int r = 0; r < 4; ++r) {
        int d = 4 * g + r;
        if (d < 13) zs[d * 33 + q] = zacc[r] * rd;
    }
    __syncthreads();

    // Zc = Wz [Zh; Zm]
    for (int idx = tid; idx < 416; idx += 256) {
        int d = idx >> 5, p = idx & 31;
        float a = 0.f;
#pragma unroll
        for (int ci = 0; ci < 13; ++ci)
            a += s_wz[d * 26 + ci] * s_zh[ci * 33 + p]
               + s_wz[d * 26 + 13 + ci] * s_zm[ci * 33 + p];
        s_zc[d * 33 + p] = a;
    }
    __syncthreads();

    // comb = Wm [Zc; hf]; update m, h
    for (int idx = tid; idx < 416; idx += 256) {
        int d = idx >> 5, p = idx & 31;
        float mo = 0.f, mg = 0.f, mi = 0.f;
#pragma unroll
        for (int ci = 0; ci < 13; ++ci) {
            float zc = s_zc[ci * 33 + p];
            mo += s_wm[d * 26 + ci] * zc;
            mg += s_wm[(13 + d) * 26 + ci] * zc;
            mi += s_wm[(26 + d) * 26 + ci] * zc;
        }
#pragma unroll
        for (int ci = 0; ci < 13; ++ci) {
            float hc = s_hf[ci * 33 + p];
            mo += s_wm[d * 26 + 13 + ci] * hc;
            mg += s_wm[(13 + d) * 26 + 13 + ci] * hc;
            mi += s_wm[(26 + d) * 26 + 13 + ci] * hc;
        }
        mi = sigmoidf_(mi);
        const size_t gi = bbN + (size_t)d * N + n0 + p;
        float mn = (1.f - mi) * m[gi] + mi * tanhf(mg);
        m[gi] = mn;
        h[gi] = sigmoidf_(mo) * mn;
    }
}

// ---------------------------------------------------------------- final 1x1 conv + log_softmax (unchanged)
__global__ __launch_bounds__(256) void k_final(
    const float* __restrict__ c, const float* __restrict__ Wf,
    const float* __restrict__ bf, float* __restrict__ out)
{
    const int i = blockIdx.x * 256 + threadIdx.x;
    const int b = i >> 10, pix = i & 1023;
    const size_t base = (size_t)b * D * N + pix;
    float cv[13];
#pragma unroll
    for (int d = 0; d < 13; ++d) cv[d] = c[base + (size_t)d * N];
    float lg[8]; float mx = -1e30f;
#pragma unroll
    for (int k = 0; k < 8; ++k) {
        float a = bf[k];
#pragma unroll
        for (int d = 0; d < 13; ++d) a += Wf[k * 13 + d] * cv[d];
        lg[k] = a; mx = fmaxf(mx, a);
    }
    float s = 0.f;
#pragma unroll
    for (int k = 0; k < 8; ++k) s += __expf(lg[k] - mx);
    float lse = mx + logf(s);
    const size_t ob = (size_t)b * 8 * N + pix;
#pragma unroll
    for (int k = 0; k < 8; ++k) out[ob + (size_t)k * N] = lg[k] - lse;
}

// ---------------------------------------------------------------- host launcher
extern "C" void kernel_launch(void* const* d_in, const int* in_sizes, int n_in,
                              void* d_out, int out_size, void* d_ws, size_t ws_size,
                              hipStream_t stream) {
    const float* x1  = (const float*)d_in[0];
    const float* Wg  = (const float*)d_in[1];
    const float* Wq  = (const float*)d_in[2];
    const float* Wkh = (const float*)d_in[3];
    const float* Wvh = (const float*)d_in[4];
    const float* Wkm = (const float*)d_in[5];
    const float* Wvm = (const float*)d_in[6];
    const float* Wz  = (const float*)d_in[7];
    const float* Wm  = (const float*)d_in[8];
    const float* Wf  = (const float*)d_in[9];
    const float* bf  = (const float*)d_in[10];

    float* ws    = (float*)d_ws;
    float* c     = ws;
    float* h     = ws + (size_t)SZ;
    float* m     = ws + (size_t)2 * SZ;
    float* h_tmp = ws + (size_t)3 * SZ;
    float* gates = ws + (size_t)4 * SZ;      // 4*SZ floats

    unsigned short* bstart = (unsigned short*)(ws + (size_t)8 * SZ);
    unsigned short* qT  = bstart;                          // [B][N][16]
    unsigned short* khT = qT  + (size_t)16 * B * N;        // [B][N][16]
    unsigned short* kmT = khT + (size_t)16 * B * N;        // [B][N][16]
    unsigned short* vhp = kmT + (size_t)16 * B * N;        // [B][13][N]
    unsigned short* vmp = vhp + (size_t)13 * B * N;        // [B][13][N]

    k_zero<<<(3 * SZ + 255) / 256, 256, 0, stream>>>(ws, 3 * SZ);

    for (int t = 0; t < T; ++t) {
        k_conv<<<dim3(4, 32, 4), 256, 0, stream>>>(x1, Wg, h, gates, t);
        k_point<<<(B * N) / 256, 256, 0, stream>>>(gates, c, m, h_tmp,
                                                   qT, khT, kmT, vhp, vmp,
                                                   Wq, Wkh, Wvh, Wkm, Wvm);
        k_attn<<<dim3(32, 32), 256, 0, stream>>>(qT, khT, kmT, vhp, vmp, h_tmp,
                                                 Wz, Wm, m, h);
    }
    k_final<<<(B * N) / 256, 256, 0, stream>>>(c, Wf, bf, (float*)d_out);
}

// Round 3
// 1878.377 us; speedup vs baseline: 2.7295x; 1.0852x over previous
//
#include <hip/hip_runtime.h>
#include <math.h>

// Problem constants
constexpr int B  = 32;
constexpr int T  = 24;
constexpr int D  = 13;
constexpr int N  = 1024;   // 32*32 spatial
constexpr int SZ = B * D * N;

typedef __attribute__((ext_vector_type(8))) short bf16x8;
typedef __attribute__((ext_vector_type(4))) float f32x4;

__device__ __forceinline__ float sigmoidf_(float x) { return 1.f / (1.f + __expf(-x)); }
__device__ __forceinline__ float tanhf_(float x) {
    float e = __expf(2.f * x);
    return 1.f - 2.f / (e + 1.f);     // exact at +-inf saturation
}

__device__ __forceinline__ unsigned short f2bf(float f) {
    unsigned u = __float_as_uint(f);
    u += 0x8000u;                     // round-half-up (cheap; error << threshold)
    return (unsigned short)(u >> 16);
}
// pack two floats -> two bf16 in one u32 (lo in bits 0..15): 2 adds + v_perm
__device__ __forceinline__ unsigned pk2bf(float lo, float hi) {
    unsigned a = __float_as_uint(lo) + 0x8000u;
    unsigned b = __float_as_uint(hi) + 0x8000u;
    return __builtin_amdgcn_perm(b, a, 0x07060302u);
}

// ---------------------------------------------------------------- zero init
__global__ void k_zero(float* __restrict__ p, int n) {
    int i = blockIdx.x * 256 + threadIdx.x;
    if (i < n) p[i] = 0.f;
}

// ---------------------------------------------------------------- weight reorder for k_cp
// wr[((q*26+ci)*9+tap)*13+cl] = Wg[((q*13+cl)*26+ci)*9+tap]
__global__ void k_wprep(const float* __restrict__ Wg, float* __restrict__ wr) {
    int i = blockIdx.x * 256 + threadIdx.x;
    if (i < 4 * 26 * 9 * 13) {
        int cl = i % 13; int r = i / 13;
        int tap = r % 9; r /= 9;
        int ci = r % 26; int q = r / 26;
        wr[i] = Wg[((q * 13 + cl) * 26 + ci) * 9 + tap];
    }
}

// ---------------------------------------------------------------- fused 3x3 conv + LSTM pointwise + Q/K/V projections
// grid (16 row-tiles, 32 batch), block 256 = 4 waves. Tile = 2 rows = 64 pixels.
// Conv: wave w computes co channels [13w,13w+13) for all 64 pixels; weights are
// wave-uniform -> s_load stream, inner loop pure v_fmac (SGPR weight operand).
// Gates exchanged via LDS; then LSTM pointwise (d split across waves) and the
// five 13x13 projections (split across waves).
__global__ __launch_bounds__(256) void k_cp(
    const float* __restrict__ x1, const float* __restrict__ wr,
    const float* __restrict__ h, float* __restrict__ c, const float* __restrict__ m_in,
    float* __restrict__ h_tmp,
    unsigned short* __restrict__ qT, unsigned short* __restrict__ khT,
    unsigned short* __restrict__ kmT, unsigned short* __restrict__ vh,
    unsigned short* __restrict__ vm,
    const float* __restrict__ Wq, const float* __restrict__ Wkh, const float* __restrict__ Wvh,
    const float* __restrict__ Wkm, const float* __restrict__ Wvm, int t)
{
    __shared__ float s_g[52][64];
    __shared__ float s_ht[13][64];
    __shared__ float s_mv[13][64];

    const int tile = blockIdx.x, b = blockIdx.y;
    const int tid = threadIdx.x;
    const int w = __builtin_amdgcn_readfirstlane(tid >> 6);   // force SGPR (uniform)
    const int lane = tid & 63;
    const int y = tile * 2 + (lane >> 5), x = lane & 31;
    const int pix = y * 32 + x;
    const size_t bb = (size_t)b * D * N;
    const float* xt = x1 + ((size_t)b * T + t) * D * N;

    // ---- conv phase: 13 output channels per wave
    float acc[13];
#pragma unroll
    for (int cl = 0; cl < 13; ++cl) acc[cl] = 0.f;

    const float* wbase = wr + (size_t)w * 26 * 117;
    for (int ci = 0; ci < 26; ++ci) {
        const float* src = (ci < 13) ? (xt + ci * N) : (h + bb + (size_t)(ci - 13) * N);
        float tv[9];
#pragma unroll
        for (int ky = 0; ky < 3; ++ky) {
            const int gy = y + ky - 1;
            const bool oky = (unsigned)gy < 32u;
#pragma unroll
            for (int kx = 0; kx < 3; ++kx) {
                const int gx = x + kx - 1;
                tv[ky * 3 + kx] = (oky && (unsigned)gx < 32u) ? src[gy * 32 + gx] : 0.f;
            }
        }
        const float* wci = wbase + ci * 117;
#pragma unroll
        for (int tap = 0; tap < 9; ++tap) {
            const float v = tv[tap];
#pragma unroll
            for (int cl = 0; cl < 13; ++cl)
                acc[cl] = fmaf(wci[tap * 13 + cl], v, acc[cl]);
        }
    }
#pragma unroll
    for (int cl = 0; cl < 13; ++cl) s_g[w * 13 + cl][lane] = acc[cl];
    __syncthreads();

    // ---- LSTM pointwise, d = {w, w+4, w+8, w+12} per wave
    for (int dd = w; dd < 13; dd += 4) {
        float ig = sigmoidf_(s_g[dd][lane]);
        float fg = sigmoidf_(s_g[13 + dd][lane]);
        float gg = tanhf_(s_g[26 + dd][lane]);
        float og = sigmoidf_(s_g[39 + dd][lane]);
        const size_t gi = bb + (size_t)dd * N + pix;
        float cn = fg * c[gi] + ig * gg;
        c[gi] = cn;
        float hv = og * tanhf_(cn);
        h_tmp[gi] = hv;
        s_ht[dd][lane] = hv;
        s_mv[dd][lane] = m_in[gi];
    }
    __syncthreads();

    // ---- projections (weights wave-uniform -> s_load)
    const size_t ro = ((size_t)b * N + pix) * 16;
    if (w == 0) {               // q -> qT
        float htv[13];
#pragma unroll
        for (int j = 0; j < 13; ++j) htv[j] = s_ht[j][lane];
        float o[16];
#pragma unroll
        for (int d = 0; d < 13; ++d) {
            float a = 0.f;
#pragma unroll
            for (int j = 0; j < 13; ++j) a = fmaf(Wq[d * 13 + j], htv[j], a);
            o[d] = a;
        }
        o[13] = o[14] = o[15] = 0.f;
        uint4 w0, w1;
        w0.x = pk2bf(o[0], o[1]);  w0.y = pk2bf(o[2], o[3]);
        w0.z = pk2bf(o[4], o[5]);  w0.w = pk2bf(o[6], o[7]);
        w1.x = pk2bf(o[8], o[9]);  w1.y = pk2bf(o[10], o[11]);
        w1.z = pk2bf(o[12], 0.f);  w1.w = 0u;
        ((uint4*)(qT + ro))[0] = w0; ((uint4*)(qT + ro))[1] = w1;
    } else if (w == 1) {        // kh -> khT, vh (d-major bf16)
        float htv[13];
#pragma unroll
        for (int j = 0; j < 13; ++j) htv[j] = s_ht[j][lane];
        float o[16];
#pragma unroll
        for (int d = 0; d < 13; ++d) {
            float a = 0.f;
#pragma unroll
            for (int j = 0; j < 13; ++j) a = fmaf(Wkh[d * 13 + j], htv[j], a);
            o[d] = a;
        }
        uint4 w0, w1;
        w0.x = pk2bf(o[0], o[1]);  w0.y = pk2bf(o[2], o[3]);
        w0.z = pk2bf(o[4], o[5]);  w0.w = pk2bf(o[6], o[7]);
        w1.x = pk2bf(o[8], o[9]);  w1.y = pk2bf(o[10], o[11]);
        w1.z = pk2bf(o[12], 0.f);  w1.w = 0u;
        ((uint4*)(khT + ro))[0] = w0; ((uint4*)(khT + ro))[1] = w1;
#pragma unroll
        for (int d = 0; d < 13; ++d) {
            float a = 0.f;
#pragma unroll
            for (int j = 0; j < 13; ++j) a = fmaf(Wvh[d * 13 + j], htv[j], a);
            vh[bb + (size_t)d * N + pix] = f2bf(a);
        }
    } else if (w == 2) {        // km -> kmT, vm
        float mvv[13];
#pragma unroll
        for (int j = 0; j < 13; ++j) mvv[j] = s_mv[j][lane];
        float o[16];
#pragma unroll
        for (int d = 0; d < 13; ++d) {
            float a = 0.f;
#pragma unroll
            for (int j = 0; j < 13; ++j) a = fmaf(Wkm[d * 13 + j], mvv[j], a);
            o[d] = a;
        }
        uint4 w0, w1;
        w0.x = pk2bf(o[0], o[1]);  w0.y = pk2bf(o[2], o[3]);
        w0.z = pk2bf(o[4], o[5]);  w0.w = pk2bf(o[6], o[7]);
        w1.x = pk2bf(o[8], o[9]);  w1.y = pk2bf(o[10], o[11]);
        w1.z = pk2bf(o[12], 0.f);  w1.w = 0u;
        ((uint4*)(kmT + ro))[0] = w0; ((uint4*)(kmT + ro))[1] = w1;
#pragma unroll
        for (int d = 0; d < 13; ++d) {
            float a = 0.f;
#pragma unroll
            for (int j = 0; j < 13; ++j) a = fmaf(Wvm[d * 13 + j], mvv[j], a);
            vm[bb + (size_t)d * N + pix] = f2bf(a);
        }
    }
}

// ---------------------------------------------------------------- MFMA dual attention + fused SAM epilogue
__global__ __launch_bounds__(256) void k_attn(
    const unsigned short* __restrict__ qT, const unsigned short* __restrict__ khT,
    const unsigned short* __restrict__ kmT, const unsigned short* __restrict__ vh,
    const unsigned short* __restrict__ vm, const float* __restrict__ h_tmp,
    const float* __restrict__ Wz, const float* __restrict__ Wm,
    float* __restrict__ m, float* __restrict__ h)
{
    __shared__ __align__(16) unsigned short s_k[2][64 * 24]; // [br][key*24 + d]
    __shared__ __align__(16) unsigned short s_v[2][16 * 72]; // [br][d*72 + key]
    __shared__ float s_hf[13 * 33];
    __shared__ float s_zh[13 * 33], s_zm[13 * 33], s_zc[13 * 33];
    __shared__ float s_wz[13 * 26];
    __shared__ float s_wm[39 * 26];

    const int b = blockIdx.y, n0 = blockIdx.x * 32, tid = threadIdx.x;
    const int lane = tid & 63, w = tid >> 6;
    const int g = lane >> 4, l15 = lane & 15;
    const int br = w >> 1;
    const size_t bbN = (size_t)b * D * N;

    for (int idx = tid; idx < 13 * 26; idx += 256) s_wz[idx] = Wz[idx];
    for (int idx = tid; idx < 39 * 26; idx += 256) s_wm[idx] = Wm[idx];
    for (int idx = tid; idx < 13 * 32; idx += 256) {
        int d = idx >> 5, p = idx & 31;
        s_hf[d * 33 + p] = h_tmp[bbN + (size_t)d * N + n0 + p];
    }
    for (int idx = tid; idx < 2 * 3 * 72; idx += 256) {
        int br2 = idx / 216, rem = idx % 216;
        s_v[br2][13 * 72 + rem] = 0;
    }

    bf16x8 b1 = {0, 0, 0, 0, 0, 0, 0, 0};
    if (g < 2) {
        const unsigned short* qp = qT + ((size_t)b * N + n0 + (w & 1) * 16 + l15) * 16 + 8 * g;
        b1 = *(const bf16x8*)qp;
    }

    f32x4 zacc = {0.f, 0.f, 0.f, 0.f};
    float den = 0.f;

    for (int cc = 0; cc < 16; ++cc) {
        __syncthreads();
        {   // stage K (both branches)
            int br2 = tid >> 7, row = (tid >> 1) & 63, part = tid & 1;
            const unsigned short* src = (br2 ? kmT : khT)
                + ((size_t)b * N + cc * 64 + row) * 16 + part * 8;
            *(uint4*)&s_k[br2][row * 24 + part * 8] = *(const uint4*)src;
        }
        if (tid < 208) {  // stage V
            int br2 = tid >= 104;
            int rem = tid - 104 * br2;
            int d = rem >> 3, part = rem & 7;
            const unsigned short* src = (br2 ? vm : vh)
                + bbN + (size_t)d * N + cc * 64 + part * 8;
            *(uint4*)&s_v[br2][d * 72 + part * 8] = *(const uint4*)src;
        }
        __syncthreads();

#pragma unroll
        for (int u = 0; u < 2; ++u) {
            bf16x8 a0 = {0, 0, 0, 0, 0, 0, 0, 0}, a1v = {0, 0, 0, 0, 0, 0, 0, 0};
            if (g < 2) {
                const int rbase = 32 * u + 8 * (l15 >> 2) + (l15 & 3);
                a0  = *(const bf16x8*)&s_k[br][(rbase)     * 24 + 8 * g];
                a1v = *(const bf16x8*)&s_k[br][(rbase + 4) * 24 + 8 * g];
            }
            f32x4 d0 = {0.f, 0.f, 0.f, 0.f}, d1 = {0.f, 0.f, 0.f, 0.f};
            d0 = __builtin_amdgcn_mfma_f32_16x16x32_bf16(a0,  b1, d0, 0, 0, 0);
            d1 = __builtin_amdgcn_mfma_f32_16x16x32_bf16(a1v, b1, d1, 0, 0, 0);

            float e0[4], e1[4];
#pragma unroll
            for (int r = 0; r < 4; ++r) { e0[r] = __expf(d0[r]); e1[r] = __expf(d1[r]); }
            den += ((e0[0] + e0[1]) + (e0[2] + e0[3])) + ((e1[0] + e1[1]) + (e1[2] + e1[3]));

            union { int4 iv; bf16x8 v; } u2;
            u2.iv.x = (int)pk2bf(e0[0], e0[1]);
            u2.iv.y = (int)pk2bf(e0[2], e0[3]);
            u2.iv.z = (int)pk2bf(e1[0], e1[1]);
            u2.iv.w = (int)pk2bf(e1[2], e1[3]);

            bf16x8 a2 = *(const bf16x8*)&s_v[br][l15 * 72 + 32 * u + 8 * g];
            zacc = __builtin_amdgcn_mfma_f32_16x16x32_bf16(a2, u2.v, zacc, 0, 0, 0);
        }
    }

    den += __shfl_xor(den, 16, 64);
    den += __shfl_xor(den, 32, 64);
    const float rd = 1.f / den;

    float* zs = br ? s_zm : s_zh;
    const int q = (w & 1) * 16 + l15;
#pragma unroll
    for (int r = 0; r < 4; ++r) {
        int d = 4 * g + r;
        if (d < 13) zs[d * 33 + q] = zacc[r] * rd;
    }
    __syncthreads();

    for (int idx = tid; idx < 416; idx += 256) {
        int d = idx >> 5, p = idx & 31;
        float a = 0.f;
#pragma unroll
        for (int ci = 0; ci < 13; ++ci)
            a += s_wz[d * 26 + ci] * s_zh[ci * 33 + p]
               + s_wz[d * 26 + 13 + ci] * s_zm[ci * 33 + p];
        s_zc[d * 33 + p] = a;
    }
    __syncthreads();

    for (int idx = tid; idx < 416; idx += 256) {
        int d = idx >> 5, p = idx & 31;
        float mo = 0.f, mg = 0.f, mi = 0.f;
#pragma unroll
        for (int ci = 0; ci < 13; ++ci) {
            float zc = s_zc[ci * 33 + p];
            mo += s_wm[d * 26 + ci] * zc;
            mg += s_wm[(13 + d) * 26 + ci] * zc;
            mi += s_wm[(26 + d) * 26 + ci] * zc;
        }
#pragma unroll
        for (int ci = 0; ci < 13; ++ci) {
            float hc = s_hf[ci * 33 + p];
            mo += s_wm[d * 26 + 13 + ci] * hc;
            mg += s_wm[(13 + d) * 26 + 13 + ci] * hc;
            mi += s_wm[(26 + d) * 26 + 13 + ci] * hc;
        }
        mi = sigmoidf_(mi);
        const size_t gi = bbN + (size_t)d * N + n0 + p;
        float mn = (1.f - mi) * m[gi] + mi * tanhf_(mg);
        m[gi] = mn;
        h[gi] = sigmoidf_(mo) * mn;
    }
}

// ---------------------------------------------------------------- final 1x1 conv + log_softmax
__global__ __launch_bounds__(256) void k_final(
    const float* __restrict__ c, const float* __restrict__ Wf,
    const float* __restrict__ bf, float* __restrict__ out)
{
    const int i = blockIdx.x * 256 + threadIdx.x;
    const int b = i >> 10, pix = i & 1023;
    const size_t base = (size_t)b * D * N + pix;
    float cv[13];
#pragma unroll
    for (int d = 0; d < 13; ++d) cv[d] = c[base + (size_t)d * N];
    float lg[8]; float mx = -1e30f;
#pragma unroll
    for (int k = 0; k < 8; ++k) {
        float a = bf[k];
#pragma unroll
        for (int d = 0; d < 13; ++d) a += Wf[k * 13 + d] * cv[d];
        lg[k] = a; mx = fmaxf(mx, a);
    }
    float s = 0.f;
#pragma unroll
    for (int k = 0; k < 8; ++k) s += __expf(lg[k] - mx);
    float lse = mx + logf(s);
    const size_t ob = (size_t)b * 8 * N + pix;
#pragma unroll
    for (int k = 0; k < 8; ++k) out[ob + (size_t)k * N] = lg[k] - lse;
}

// ---------------------------------------------------------------- host launcher
extern "C" void kernel_launch(void* const* d_in, const int* in_sizes, int n_in,
                              void* d_out, int out_size, void* d_ws, size_t ws_size,
                              hipStream_t stream) {
    const float* x1  = (const float*)d_in[0];
    const float* Wg  = (const float*)d_in[1];
    const float* Wq  = (const float*)d_in[2];
    const float* Wkh = (const float*)d_in[3];
    const float* Wvh = (const float*)d_in[4];
    const float* Wkm = (const float*)d_in[5];
    const float* Wvm = (const float*)d_in[6];
    const float* Wz  = (const float*)d_in[7];
    const float* Wm  = (const float*)d_in[8];
    const float* Wf  = (const float*)d_in[9];
    const float* bf  = (const float*)d_in[10];

    float* ws    = (float*)d_ws;
    float* c     = ws;
    float* h     = ws + (size_t)SZ;
    float* m     = ws + (size_t)2 * SZ;
    float* h_tmp = ws + (size_t)3 * SZ;

    unsigned short* bstart = (unsigned short*)(ws + (size_t)4 * SZ);
    unsigned short* qT  = bstart;                          // [B][N][16]
    unsigned short* khT = qT  + (size_t)16 * B * N;
    unsigned short* kmT = khT + (size_t)16 * B * N;
    unsigned short* vhp = kmT + (size_t)16 * B * N;        // [B][13][N]
    unsigned short* vmp = vhp + (size_t)13 * B * N;
    float* wr = (float*)(vmp + (size_t)13 * B * N);        // 4*26*9*13 floats

    k_zero<<<(3 * SZ + 255) / 256, 256, 0, stream>>>(ws, 3 * SZ);
    k_wprep<<<48, 256, 0, stream>>>(Wg, wr);

    for (int t = 0; t < T; ++t) {
        k_cp<<<dim3(16, 32), 256, 0, stream>>>(x1, wr, h, c, m, h_tmp,
                                               qT, khT, kmT, vhp, vmp,
                                               Wq, Wkh, Wvh, Wkm, Wvm, t);
        k_attn<<<dim3(32, 32), 256, 0, stream>>>(qT, khT, kmT, vhp, vmp, h_tmp,
                                                 Wz, Wm, m, h);
    }
    k_final<<<(B * N) / 256, 256, 0, stream>>>(c, Wf, bf, (float*)d_out);
}

// Round 6
// 1673.771 us; speedup vs baseline: 3.0631x; 1.1222x over previous
//
#include <hip/hip_runtime.h>
#include <math.h>

// Problem constants
constexpr int B  = 32;
constexpr int T  = 24;
constexpr int D  = 13;
constexpr int N  = 1024;   // 32*32 spatial
constexpr int SZ = B * D * N;

typedef __attribute__((ext_vector_type(8))) short bf16x8;
typedef __attribute__((ext_vector_type(4))) float f32x4;

__device__ __forceinline__ float sigmoidf_(float x) { return 1.f / (1.f + __expf(-x)); }
__device__ __forceinline__ float tanhf_(float x) {
    float e = __expf(2.f * x);
    return 1.f - 2.f / (e + 1.f);
}

__device__ __forceinline__ unsigned short f2bf(float f) {
    unsigned u = __float_as_uint(f);
    u += 0x8000u;
    return (unsigned short)(u >> 16);
}
__device__ __forceinline__ unsigned pk2bf(float lo, float hi) {
    unsigned a = __float_as_uint(lo) + 0x8000u;
    unsigned b = __float_as_uint(hi) + 0x8000u;
    return __builtin_amdgcn_perm(b, a, 0x07060302u);
}

// ---------------------------------------------------------------- zero init
__global__ void k_zero(float* __restrict__ p, int n) {
    int i = blockIdx.x * 256 + threadIdx.x;
    if (i < n) p[i] = 0.f;
}

// ---------------------------------------------------------------- weight reorder for k_cp
__global__ void k_wprep(const float* __restrict__ Wg, float* __restrict__ wr) {
    int i = blockIdx.x * 256 + threadIdx.x;
    if (i < 4 * 26 * 9 * 13) {
        int cl = i % 13; int r = i / 13;
        int tap = r % 9; r /= 9;
        int ci = r % 26; int q = r / 26;
        wr[i] = Wg[((q * 13 + cl) * 26 + ci) * 9 + tap];
    }
}

// ---------------------------------------------------------------- fused conv + LSTM pointwise + Q/K/V projections
// grid (16 row-tiles, 32 batch), block 256 = 4 waves; tile = 2 rows (64 px).
// Stencil inputs LDS-staged with halo (zero-padded); weights wave-uniform ->
// s_load stream; conv inner loop pure v_fmac (SGPR weight, VGPR stencil value).
__global__ __launch_bounds__(256) void k_cp(
    const float* __restrict__ x1, const float* __restrict__ wr,
    const float* __restrict__ h, float* __restrict__ c, const float* __restrict__ m_in,
    float* __restrict__ h_tmp,
    unsigned short* __restrict__ qT, unsigned short* __restrict__ khT,
    unsigned short* __restrict__ kmT, unsigned short* __restrict__ vh,
    unsigned short* __restrict__ vm,
    const float* __restrict__ Wq, const float* __restrict__ Wkh, const float* __restrict__ Wvh,
    const float* __restrict__ Wkm, const float* __restrict__ Wvm, int t)
{
    __shared__ float s_in[26 * 136 + 8];   // [ci][4 rows][34 cols]
    __shared__ float s_g[52][64];
    __shared__ float s_ht[13][64];
    __shared__ float s_mv[13][64];

    const int tile = blockIdx.x, b = blockIdx.y;
    const int tid = threadIdx.x;
    const int w = __builtin_amdgcn_readfirstlane(tid >> 6);
    const int lane = tid & 63;
    const int ry = lane >> 5, x = lane & 31;
    const int y = tile * 2 + ry;
    const int pix = y * 32 + x;
    const size_t bb = (size_t)b * D * N;
    const float* xt = x1 + ((size_t)b * T + t) * D * N;

    // stage 26ch x 4 rows (y0-1..y0+2) x 34 cols (x -1..32), zeros outside
    for (int idx = tid; idx < 3536; idx += 256) {
        int ci = idx / 136, rem = idx % 136;
        int r = rem / 34, col = rem % 34;
        int gy = tile * 2 - 1 + r, gx = col - 1;
        float v = 0.f;
        if ((unsigned)gy < 32u && (unsigned)gx < 32u) {
            const float* src = (ci < 13) ? (xt + (size_t)ci * N) : (h + bb + (size_t)(ci - 13) * N);
            v = src[gy * 32 + gx];
        }
        s_in[idx] = v;
    }
    __syncthreads();

    // ---- conv: wave w -> output channels [13w, 13w+13)
    float acc[13];
#pragma unroll
    for (int cl = 0; cl < 13; ++cl) acc[cl] = 0.f;

    const float* wbase = wr + (size_t)w * 26 * 117;
    for (int ci = 0; ci < 26; ++ci) {
        const float* sb = &s_in[ci * 136 + ry * 34 + x];
        float tv[9];
#pragma unroll
        for (int ky = 0; ky < 3; ++ky)
#pragma unroll
            for (int kx = 0; kx < 3; ++kx)
                tv[ky * 3 + kx] = sb[ky * 34 + kx];
        const float* wci = wbase + ci * 117;
#pragma unroll
        for (int tap = 0; tap < 9; ++tap) {
            const float v = tv[tap];
#pragma unroll
            for (int cl = 0; cl < 13; ++cl)
                acc[cl] = fmaf(wci[tap * 13 + cl], v, acc[cl]);
        }
    }
#pragma unroll
    for (int cl = 0; cl < 13; ++cl) s_g[w * 13 + cl][lane] = acc[cl];
    __syncthreads();

    // ---- LSTM pointwise, d strided over waves
    for (int dd = w; dd < 13; dd += 4) {
        float ig = sigmoidf_(s_g[dd][lane]);
        float fg = sigmoidf_(s_g[13 + dd][lane]);
        float gg = tanhf_(s_g[26 + dd][lane]);
        float og = sigmoidf_(s_g[39 + dd][lane]);
        const size_t gi = bb + (size_t)dd * N + pix;
        float cn = fg * c[gi] + ig * gg;
        c[gi] = cn;
        float hv = og * tanhf_(cn);
        h_tmp[gi] = hv;
        s_ht[dd][lane] = hv;
        s_mv[dd][lane] = m_in[gi];
    }
    __syncthreads();

    // ---- projections (weights wave-uniform -> s_load)
    const size_t ro = ((size_t)b * N + pix) * 16;
    if (w == 0) {               // q -> qT
        float htv[13];
#pragma unroll
        for (int j = 0; j < 13; ++j) htv[j] = s_ht[j][lane];
        float o[13];
#pragma unroll
        for (int d = 0; d < 13; ++d) {
            float a = 0.f;
#pragma unroll
            for (int j = 0; j < 13; ++j) a = fmaf(Wq[d * 13 + j], htv[j], a);
            o[d] = a;
        }
        uint4 w0, w1;
        w0.x = pk2bf(o[0], o[1]);  w0.y = pk2bf(o[2], o[3]);
        w0.z = pk2bf(o[4], o[5]);  w0.w = pk2bf(o[6], o[7]);
        w1.x = pk2bf(o[8], o[9]);  w1.y = pk2bf(o[10], o[11]);
        w1.z = pk2bf(o[12], 0.f);  w1.w = 0u;
        ((uint4*)(qT + ro))[0] = w0; ((uint4*)(qT + ro))[1] = w1;
    } else if (w == 1) {        // kh -> khT, vh
        float htv[13];
#pragma unroll
        for (int j = 0; j < 13; ++j) htv[j] = s_ht[j][lane];
        float o[13];
#pragma unroll
        for (int d = 0; d < 13; ++d) {
            float a = 0.f;
#pragma unroll
            for (int j = 0; j < 13; ++j) a = fmaf(Wkh[d * 13 + j], htv[j], a);
            o[d] = a;
        }
        uint4 w0, w1;
        w0.x = pk2bf(o[0], o[1]);  w0.y = pk2bf(o[2], o[3]);
        w0.z = pk2bf(o[4], o[5]);  w0.w = pk2bf(o[6], o[7]);
        w1.x = pk2bf(o[8], o[9]);  w1.y = pk2bf(o[10], o[11]);
        w1.z = pk2bf(o[12], 0.f);  w1.w = 0u;
        ((uint4*)(khT + ro))[0] = w0; ((uint4*)(khT + ro))[1] = w1;
#pragma unroll
        for (int d = 0; d < 13; ++d) {
            float a = 0.f;
#pragma unroll
            for (int j = 0; j < 13; ++j) a = fmaf(Wvh[d * 13 + j], htv[j], a);
            vh[bb + (size_t)d * N + pix] = f2bf(a);
        }
    } else if (w == 2) {        // km -> kmT, vm
        float mvv[13];
#pragma unroll
        for (int j = 0; j < 13; ++j) mvv[j] = s_mv[j][lane];
        float o[13];
#pragma unroll
        for (int d = 0; d < 13; ++d) {
            float a = 0.f;
#pragma unroll
            for (int j = 0; j < 13; ++j) a = fmaf(Wkm[d * 13 + j], mvv[j], a);
            o[d] = a;
        }
        uint4 w0, w1;
        w0.x = pk2bf(o[0], o[1]);  w0.y = pk2bf(o[2], o[3]);
        w0.z = pk2bf(o[4], o[5]);  w0.w = pk2bf(o[6], o[7]);
        w1.x = pk2bf(o[8], o[9]);  w1.y = pk2bf(o[10], o[11]);
        w1.z = pk2bf(o[12], 0.f);  w1.w = 0u;
        ((uint4*)(kmT + ro))[0] = w0; ((uint4*)(kmT + ro))[1] = w1;
#pragma unroll
        for (int d = 0; d < 13; ++d) {
            float a = 0.f;
#pragma unroll
            for (int j = 0; j < 13; ++j) a = fmaf(Wvm[d * 13 + j], mvv[j], a);
            vm[bb + (size_t)d * N + pix] = f2bf(a);
        }
    }
}

// ---------------------------------------------------------------- MFMA dual attention + fused SAM epilogue
// grid (32 qtiles, 32 batch), block 256 = 4 waves (proven round-2/3 shape).
// wave w: branch = w>>1, query group = w&1 (16 queries). 128-key chunks,
// single-buffered: 2 barriers/chunk x 8 chunks. Softmax denominator comes free
// from the PV MFMA via V pad-row 13 == 1.0 (den at lane 48+l15, reg 1).
__global__ __launch_bounds__(256) void k_attn(
    const unsigned short* __restrict__ qT, const unsigned short* __restrict__ khT,
    const unsigned short* __restrict__ kmT, const unsigned short* __restrict__ vh,
    const unsigned short* __restrict__ vm, const float* __restrict__ h_tmp,
    const float* __restrict__ Wz, const float* __restrict__ Wm,
    float* __restrict__ m, float* __restrict__ h)
{
    __shared__ __align__(16) unsigned short s_k[2][128 * 24]; // [br][key*24 + d]
    __shared__ __align__(16) unsigned short s_v[2][16 * 136]; // [br][d*136 + key]
    __shared__ float s_hf[13 * 33];
    __shared__ float s_zh[13 * 33], s_zm[13 * 33], s_zc[13 * 33];
    __shared__ float s_wz[13 * 26];
    __shared__ float s_wm[39 * 26];

    const int b = blockIdx.y, n0 = blockIdx.x * 32, tid = threadIdx.x;
    const int lane = tid & 63, w = tid >> 6;
    const int g = lane >> 4, l15 = lane & 15;
    const int br = w >> 1, qg = w & 1;
    const size_t bbN = (size_t)b * D * N;

    for (int idx = tid; idx < 13 * 26; idx += 256) s_wz[idx] = Wz[idx];
    for (int idx = tid; idx < 39 * 26; idx += 256) s_wm[idx] = Wm[idx];
    for (int idx = tid; idx < 13 * 32; idx += 256) {
        int d = idx >> 5, p = idx & 31;
        s_hf[d * 33 + p] = h_tmp[bbN + (size_t)d * N + n0 + p];
    }
    // V pad rows: row 13 = bf16 1.0 (free denominator), rows 14/15 = 0.
    // Written once; chunk staging only touches rows 0..12.
    for (int idx = tid; idx < 2 * 3 * 136; idx += 256) {
        int keyp = idx % 136;
        int r = idx / 136;               // br*3 + row
        int row = r % 3, br2 = r / 3;
        s_v[br2][(13 + row) * 136 + keyp] = (row == 0) ? (unsigned short)0x3F80 : (unsigned short)0;
    }

    // constant q fragment (B operand): B1[k=d][n=query]
    bf16x8 b1 = {0, 0, 0, 0, 0, 0, 0, 0};
    if (g < 2)
        b1 = *(const bf16x8*)(qT + ((size_t)b * N + n0 + qg * 16 + l15) * 16 + 8 * g);

    f32x4 zacc = {0.f, 0.f, 0.f, 0.f};

    for (int cc = 0; cc < 8; ++cc) {
        __syncthreads();
        // stage K: 2 br x 128 rows x 2 parts = 512 x 16B pieces
        for (int idx = tid; idx < 512; idx += 256) {
            int br2 = idx >> 8, rem = idx & 255;
            int row = rem >> 1, part = rem & 1;
            const unsigned short* src = (br2 ? kmT : khT)
                + ((size_t)b * N + cc * 128 + row) * 16 + part * 8;
            *(uint4*)&s_k[br2][row * 24 + part * 8] = *(const uint4*)src;
        }
        // stage V: 2 br x 13 d x 16 parts = 416 x 16B pieces
        for (int idx = tid; idx < 416; idx += 256) {
            int br2 = idx / 208, rem = idx % 208;
            int d = rem >> 4, part = rem & 15;
            const unsigned short* src = (br2 ? vm : vh)
                + bbN + (size_t)d * N + cc * 128 + part * 8;
            *(uint4*)&s_v[br2][d * 136 + part * 8] = *(const uint4*)src;
        }
        __syncthreads();

#pragma unroll
        for (int u = 0; u < 4; ++u) {
            bf16x8 a0 = {0, 0, 0, 0, 0, 0, 0, 0}, a1v = {0, 0, 0, 0, 0, 0, 0, 0};
            if (g < 2) {
                const int rbase = 32 * u + 8 * (l15 >> 2) + (l15 & 3);
                a0  = *(const bf16x8*)&s_k[br][(rbase)     * 24 + 8 * g];
                a1v = *(const bf16x8*)&s_k[br][(rbase + 4) * 24 + 8 * g];
            }
            f32x4 d0 = {0.f, 0.f, 0.f, 0.f}, d1 = {0.f, 0.f, 0.f, 0.f};
            d0 = __builtin_amdgcn_mfma_f32_16x16x32_bf16(a0,  b1, d0, 0, 0, 0);
            d1 = __builtin_amdgcn_mfma_f32_16x16x32_bf16(a1v, b1, d1, 0, 0, 0);

            float e0[4], e1[4];
#pragma unroll
            for (int r = 0; r < 4; ++r) { e0[r] = __expf(d0[r]); e1[r] = __expf(d1[r]); }

            union { int4 iv; bf16x8 v; } u2;
            u2.iv.x = (int)pk2bf(e0[0], e0[1]);
            u2.iv.y = (int)pk2bf(e0[2], e0[3]);
            u2.iv.z = (int)pk2bf(e1[0], e1[1]);
            u2.iv.w = (int)pk2bf(e1[2], e1[3]);

            bf16x8 a2 = *(const bf16x8*)&s_v[br][l15 * 136 + 32 * u + 8 * g];
            zacc = __builtin_amdgcn_mfma_f32_16x16x32_bf16(a2, u2.v, zacc, 0, 0, 0);
        }
    }

    // denominator = accumulator row 13 (V pad row of ones): lane 48+l15, reg 1
    const float den = __shfl(zacc[1], 48 + l15, 64);
    const float rd = 1.f / den;

    float* zs = br ? s_zm : s_zh;
    const int q = qg * 16 + l15;
#pragma unroll
    for (int r = 0; r < 4; ++r) {
        int d = 4 * g + r;
        if (d < 13) zs[d * 33 + q] = zacc[r] * rd;
    }
    __syncthreads();

    // Zc = Wz [Zh; Zm]
    for (int idx = tid; idx < 416; idx += 256) {
        int d = idx >> 5, p = idx & 31;
        float a = 0.f;
#pragma unroll
        for (int ci = 0; ci < 13; ++ci)
            a += s_wz[d * 26 + ci] * s_zh[ci * 33 + p]
               + s_wz[d * 26 + 13 + ci] * s_zm[ci * 33 + p];
        s_zc[d * 33 + p] = a;
    }
    __syncthreads();

    // comb = Wm [Zc; hf]; update m, h
    for (int idx = tid; idx < 416; idx += 256) {
        int d = idx >> 5, p = idx & 31;
        float mo = 0.f, mg = 0.f, mi = 0.f;
#pragma unroll
        for (int ci = 0; ci < 13; ++ci) {
            float zc = s_zc[ci * 33 + p];
            mo += s_wm[d * 26 + ci] * zc;
            mg += s_wm[(13 + d) * 26 + ci] * zc;
            mi += s_wm[(26 + d) * 26 + ci] * zc;
        }
#pragma unroll
        for (int ci = 0; ci < 13; ++ci) {
            float hc = s_hf[ci * 33 + p];
            mo += s_wm[d * 26 + 13 + ci] * hc;
            mg += s_wm[(13 + d) * 26 + 13 + ci] * hc;
            mi += s_wm[(26 + d) * 26 + 13 + ci] * hc;
        }
        mi = sigmoidf_(mi);
        const size_t gi = bbN + (size_t)d * N + n0 + p;
        float mn = (1.f - mi) * m[gi] + mi * tanhf_(mg);
        m[gi] = mn;
        h[gi] = sigmoidf_(mo) * mn;
    }
}

// ---------------------------------------------------------------- final 1x1 conv + log_softmax
__global__ __launch_bounds__(256) void k_final(
    const float* __restrict__ c, const float* __restrict__ Wf,
    const float* __restrict__ bf, float* __restrict__ out)
{
    const int i = blockIdx.x * 256 + threadIdx.x;
    const int b = i >> 10, pix = i & 1023;
    const size_t base = (size_t)b * D * N + pix;
    float cv[13];
#pragma unroll
    for (int d = 0; d < 13; ++d) cv[d] = c[base + (size_t)d * N];
    float lg[8]; float mx = -1e30f;
#pragma unroll
    for (int k = 0; k < 8; ++k) {
        float a = bf[k];
#pragma unroll
        for (int d = 0; d < 13; ++d) a += Wf[k * 13 + d] * cv[d];
        lg[k] = a; mx = fmaxf(mx, a);
    }
    float s = 0.f;
#pragma unroll
    for (int k = 0; k < 8; ++k) s += __expf(lg[k] - mx);
    float lse = mx + logf(s);
    const size_t ob = (size_t)b * 8 * N + pix;
#pragma unroll
    for (int k = 0; k < 8; ++k) out[ob + (size_t)k * N] = lg[k] - lse;
}

// ---------------------------------------------------------------- host launcher
extern "C" void kernel_launch(void* const* d_in, const int* in_sizes, int n_in,
                              void* d_out, int out_size, void* d_ws, size_t ws_size,
                              hipStream_t stream) {
    const float* x1  = (const float*)d_in[0];
    const float* Wg  = (const float*)d_in[1];
    const float* Wq  = (const float*)d_in[2];
    const float* Wkh = (const float*)d_in[3];
    const float* Wvh = (const float*)d_in[4];
    const float* Wkm = (const float*)d_in[5];
    const float* Wvm = (const float*)d_in[6];
    const float* Wz  = (const float*)d_in[7];
    const float* Wm  = (const float*)d_in[8];
    const float* Wf  = (const float*)d_in[9];
    const float* bf  = (const float*)d_in[10];

    float* ws    = (float*)d_ws;
    float* c     = ws;
    float* h     = ws + (size_t)SZ;
    float* m     = ws + (size_t)2 * SZ;
    float* h_tmp = ws + (size_t)3 * SZ;

    unsigned short* bstart = (unsigned short*)(ws + (size_t)4 * SZ);
    unsigned short* qT  = bstart;                          // [B][N][16]
    unsigned short* khT = qT  + (size_t)16 * B * N;
    unsigned short* kmT = khT + (size_t)16 * B * N;
    unsigned short* vhp = kmT + (size_t)16 * B * N;        // [B][13][N]
    unsigned short* vmp = vhp + (size_t)13 * B * N;
    float* wr = (float*)(vmp + (size_t)13 * B * N);        // 4*26*9*13 floats

    k_zero<<<(3 * SZ + 255) / 256, 256, 0, stream>>>(ws, 3 * SZ);
    k_wprep<<<48, 256, 0, stream>>>(Wg, wr);

    for (int t = 0; t < T; ++t) {
        k_cp<<<dim3(16, 32), 256, 0, stream>>>(x1, wr, h, c, m, h_tmp,
                                               qT, khT, kmT, vhp, vmp,
                                               Wq, Wkh, Wvh, Wkm, Wvm, t);
        k_attn<<<dim3(32, 32), 256, 0, stream>>>(qT, khT, kmT, vhp, vmp, h_tmp,
                                                 Wz, Wm, m, h);
    }
    k_final<<<(B * N) / 256, 256, 0, stream>>>(c, Wf, bf, (float*)d_out);
}

// Round 7
// 1218.853 us; speedup vs baseline: 4.2064x; 1.3732x over previous
//
#include <hip/hip_runtime.h>
#include <math.h>

// Problem constants
constexpr int B  = 32;
constexpr int T  = 24;
constexpr int D  = 13;
constexpr int N  = 1024;   // 32*32 spatial
constexpr int SZ = B * D * N;

typedef __attribute__((ext_vector_type(8))) short bf16x8;
typedef __attribute__((ext_vector_type(4))) float f32x4;

__device__ __forceinline__ float sigmoidf_(float x) { return 1.f / (1.f + __expf(-x)); }
__device__ __forceinline__ float tanhf_(float x) {
    float e = __expf(2.f * x);
    return 1.f - 2.f / (e + 1.f);
}

__device__ __forceinline__ unsigned short f2bf(float f) {
    unsigned u = __float_as_uint(f);
    u += 0x8000u;
    return (unsigned short)(u >> 16);
}
__device__ __forceinline__ unsigned pk2bf(float lo, float hi) {
    unsigned a = __float_as_uint(lo) + 0x8000u;
    unsigned b = __float_as_uint(hi) + 0x8000u;
    return __builtin_amdgcn_perm(b, a, 0x07060302u);
}

// ---------------------------------------------------------------- zero init
__global__ void k_zero(float* __restrict__ p, int n) {
    int i = blockIdx.x * 256 + threadIdx.x;
    if (i < n) p[i] = 0.f;
}

// ---------------------------------------------------------------- conv weights -> MFMA A-fragment layout (bf16)
// wrA[((ct*9+tap)*64 + lane)*8 + j] = A[m=lane&15][k=8*(lane>>4)+j] for co-tile ct, tap.
// k (channel) map: 0..12 -> x ci=k, 13..15 -> 0, 16..28 -> h ci=k-3, 29..31 -> 0.
__global__ void k_wprep(const float* __restrict__ Wg, unsigned short* __restrict__ wrA) {
    int i = blockIdx.x * 256 + threadIdx.x;
    if (i >= 4 * 9 * 64 * 8) return;
    int j = i & 7; int r = i >> 3;
    int lane = r & 63; r >>= 6;
    int tap = r % 9; int ct = r / 9;
    int m = lane & 15, g = lane >> 4;
    int k = g * 8 + j;
    int co = ct * 16 + m;
    int ci = -1;
    if (k < 13) ci = k;
    else if (k >= 16 && k < 29) ci = k - 3;
    unsigned short v = 0;
    if (co < 52 && ci >= 0) v = f2bf(Wg[(co * 26 + ci) * 9 + tap]);
    wrA[i] = v;
}

// ---------------------------------------------------------------- fused MFMA conv + LSTM pointwise + Q/K/V projections
// grid (16 row-tiles, 32 batch), block 256 = 4 waves; tile = 2 rows (64 px).
// Conv as implicit GEMM: K=32 = [x ch 0..12 | pad | h ch 0..12 | pad], one
// 16x16x32 MFMA per tap; wave w owns output-channel tile [16w,16w+16).
// A-frags preloaded (wave-constant); B-frags are single ds_read_b128 from the
// bf16 input tile at tap-shifted sites.
__global__ __launch_bounds__(256) void k_cp(
    const float* __restrict__ x1, const unsigned short* __restrict__ wrA,
    const float* __restrict__ h, float* __restrict__ c, const float* __restrict__ m_in,
    float* __restrict__ h_tmp,
    unsigned short* __restrict__ qT, unsigned short* __restrict__ khT,
    unsigned short* __restrict__ kmT, unsigned short* __restrict__ vh,
    unsigned short* __restrict__ vm,
    const float* __restrict__ Wq, const float* __restrict__ Wkh, const float* __restrict__ Wvh,
    const float* __restrict__ Wkm, const float* __restrict__ Wvm, int t)
{
    __shared__ __align__(16) unsigned short s_in[136 * 32];  // [site=row*34+col][ch32] bf16
    __shared__ float s_g[52 * 65];                           // gates, stride 65 (conflict-free scatter)
    __shared__ float s_ht[13][64];
    __shared__ float s_mv[13][64];

    const int tile = blockIdx.x, b = blockIdx.y;
    const int tid = threadIdx.x;
    const int w = __builtin_amdgcn_readfirstlane(tid >> 6);
    const int lane = tid & 63;
    const int g = lane >> 4, l15 = lane & 15;
    const int y = tile * 2 + (lane >> 5), x = lane & 31;
    const int pix = y * 32 + x;
    const size_t bb = (size_t)b * D * N;
    const float* xt = x1 + ((size_t)b * T + t) * D * N;

    // preload this wave's 9 A-fragments (co-tile = w)
    bf16x8 af[9];
#pragma unroll
    for (int tap = 0; tap < 9; ++tap)
        af[tap] = *(const bf16x8*)&wrA[(((size_t)w * 9 + tap) * 64 + lane) * 8];

    // stage input tile: 4 rows (y0-1..y0+2) x 34 cols (x -1..32), 32 ch bf16
    if (tid < 136) {
        int row = tid / 34, col = tid % 34;
        int gy = tile * 2 - 1 + row, gx = col - 1;
        bool ok = ((unsigned)gy < 32u) && ((unsigned)gx < 32u);
        int off = gy * 32 + gx;
        unsigned short tmp[32];
#pragma unroll
        for (int ch = 0; ch < 13; ++ch) {
            float xv = ok ? xt[(size_t)ch * N + off] : 0.f;
            float hv = ok ? h[bb + (size_t)ch * N + off] : 0.f;
            tmp[ch] = f2bf(xv);
            tmp[16 + ch] = f2bf(hv);
        }
        tmp[13] = tmp[14] = tmp[15] = 0;
        tmp[29] = tmp[30] = tmp[31] = 0;
        uint4* dst = (uint4*)&s_in[tid * 32];
        dst[0] = ((const uint4*)tmp)[0];
        dst[1] = ((const uint4*)tmp)[1];
        dst[2] = ((const uint4*)tmp)[2];
        dst[3] = ((const uint4*)tmp)[3];
    }
    __syncthreads();

    // ---- MFMA conv: 4 px-tiles x 9 taps
    f32x4 acc[4];
#pragma unroll
    for (int pt = 0; pt < 4; ++pt) acc[pt] = f32x4{0.f, 0.f, 0.f, 0.f};
#pragma unroll
    for (int pt = 0; pt < 4; ++pt) {
        const int px = pt * 16 + l15;
        const int r0 = px >> 5, c0 = px & 31;
#pragma unroll
        for (int tap = 0; tap < 9; ++tap) {
            const int srow = r0 + tap / 3, scol = c0 + tap % 3;
            bf16x8 bfr = *(const bf16x8*)&s_in[(srow * 34 + scol) * 32 + 8 * g];
            acc[pt] = __builtin_amdgcn_mfma_f32_16x16x32_bf16(af[tap], bfr, acc[pt], 0, 0, 0);
        }
    }
    // scatter gates to LDS: D row = co_local = 4g+rr, col = px
#pragma unroll
    for (int pt = 0; pt < 4; ++pt) {
#pragma unroll
        for (int rr = 0; rr < 4; ++rr) {
            const int co = w * 16 + 4 * g + rr;
            if (co < 52) s_g[co * 65 + pt * 16 + l15] = acc[pt][rr];
        }
    }
    __syncthreads();

    // ---- LSTM pointwise, d strided over waves
    for (int dd = w; dd < 13; dd += 4) {
        float ig = sigmoidf_(s_g[dd * 65 + lane]);
        float fg = sigmoidf_(s_g[(13 + dd) * 65 + lane]);
        float gg = tanhf_(s_g[(26 + dd) * 65 + lane]);
        float og = sigmoidf_(s_g[(39 + dd) * 65 + lane]);
        const size_t gi = bb + (size_t)dd * N + pix;
        float cn = fg * c[gi] + ig * gg;
        c[gi] = cn;
        float hv = og * tanhf_(cn);
        h_tmp[gi] = hv;
        s_ht[dd][lane] = hv;
        s_mv[dd][lane] = m_in[gi];
    }
    __syncthreads();

    // ---- projections (weights wave-uniform -> s_load)
    const size_t ro = ((size_t)b * N + pix) * 16;
    if (w == 0) {               // q -> qT
        float htv[13];
#pragma unroll
        for (int j = 0; j < 13; ++j) htv[j] = s_ht[j][lane];
        float o[13];
#pragma unroll
        for (int d = 0; d < 13; ++d) {
            float a = 0.f;
#pragma unroll
            for (int j = 0; j < 13; ++j) a = fmaf(Wq[d * 13 + j], htv[j], a);
            o[d] = a;
        }
        uint4 w0, w1;
        w0.x = pk2bf(o[0], o[1]);  w0.y = pk2bf(o[2], o[3]);
        w0.z = pk2bf(o[4], o[5]);  w0.w = pk2bf(o[6], o[7]);
        w1.x = pk2bf(o[8], o[9]);  w1.y = pk2bf(o[10], o[11]);
        w1.z = pk2bf(o[12], 0.f);  w1.w = 0u;
        ((uint4*)(qT + ro))[0] = w0; ((uint4*)(qT + ro))[1] = w1;
    } else if (w == 1) {        // kh -> khT, vh
        float htv[13];
#pragma unroll
        for (int j = 0; j < 13; ++j) htv[j] = s_ht[j][lane];
        float o[13];
#pragma unroll
        for (int d = 0; d < 13; ++d) {
            float a = 0.f;
#pragma unroll
            for (int j = 0; j < 13; ++j) a = fmaf(Wkh[d * 13 + j], htv[j], a);
            o[d] = a;
        }
        uint4 w0, w1;
        w0.x = pk2bf(o[0], o[1]);  w0.y = pk2bf(o[2], o[3]);
        w0.z = pk2bf(o[4], o[5]);  w0.w = pk2bf(o[6], o[7]);
        w1.x = pk2bf(o[8], o[9]);  w1.y = pk2bf(o[10], o[11]);
        w1.z = pk2bf(o[12], 0.f);  w1.w = 0u;
        ((uint4*)(khT + ro))[0] = w0; ((uint4*)(khT + ro))[1] = w1;
#pragma unroll
        for (int d = 0; d < 13; ++d) {
            float a = 0.f;
#pragma unroll
            for (int j = 0; j < 13; ++j) a = fmaf(Wvh[d * 13 + j], htv[j], a);
            vh[bb + (size_t)d * N + pix] = f2bf(a);
        }
    } else if (w == 2) {        // km -> kmT, vm
        float mvv[13];
#pragma unroll
        for (int j = 0; j < 13; ++j) mvv[j] = s_mv[j][lane];
        float o[13];
#pragma unroll
        for (int d = 0; d < 13; ++d) {
            float a = 0.f;
#pragma unroll
            for (int j = 0; j < 13; ++j) a = fmaf(Wkm[d * 13 + j], mvv[j], a);
            o[d] = a;
        }
        uint4 w0, w1;
        w0.x = pk2bf(o[0], o[1]);  w0.y = pk2bf(o[2], o[3]);
        w0.z = pk2bf(o[4], o[5]);  w0.w = pk2bf(o[6], o[7]);
        w1.x = pk2bf(o[8], o[9]);  w1.y = pk2bf(o[10], o[11]);
        w1.z = pk2bf(o[12], 0.f);  w1.w = 0u;
        ((uint4*)(kmT + ro))[0] = w0; ((uint4*)(kmT + ro))[1] = w1;
#pragma unroll
        for (int d = 0; d < 13; ++d) {
            float a = 0.f;
#pragma unroll
            for (int j = 0; j < 13; ++j) a = fmaf(Wvm[d * 13 + j], mvv[j], a);
            vm[bb + (size_t)d * N + pix] = f2bf(a);
        }
    }
}

// ---------------------------------------------------------------- MFMA dual attention + fused SAM epilogue
// (verbatim round-6: grid (32,32), block 256, 128-key chunks, free denominator)
__global__ __launch_bounds__(256) void k_attn(
    const unsigned short* __restrict__ qT, const unsigned short* __restrict__ khT,
    const unsigned short* __restrict__ kmT, const unsigned short* __restrict__ vh,
    const unsigned short* __restrict__ vm, const float* __restrict__ h_tmp,
    const float* __restrict__ Wz, const float* __restrict__ Wm,
    float* __restrict__ m, float* __restrict__ h)
{
    __shared__ __align__(16) unsigned short s_k[2][128 * 24]; // [br][key*24 + d]
    __shared__ __align__(16) unsigned short s_v[2][16 * 136]; // [br][d*136 + key]
    __shared__ float s_hf[13 * 33];
    __shared__ float s_zh[13 * 33], s_zm[13 * 33], s_zc[13 * 33];
    __shared__ float s_wz[13 * 26];
    __shared__ float s_wm[39 * 26];

    const int b = blockIdx.y, n0 = blockIdx.x * 32, tid = threadIdx.x;
    const int lane = tid & 63, w = tid >> 6;
    const int g = lane >> 4, l15 = lane & 15;
    const int br = w >> 1, qg = w & 1;
    const size_t bbN = (size_t)b * D * N;

    for (int idx = tid; idx < 13 * 26; idx += 256) s_wz[idx] = Wz[idx];
    for (int idx = tid; idx < 39 * 26; idx += 256) s_wm[idx] = Wm[idx];
    for (int idx = tid; idx < 13 * 32; idx += 256) {
        int d = idx >> 5, p = idx & 31;
        s_hf[d * 33 + p] = h_tmp[bbN + (size_t)d * N + n0 + p];
    }
    for (int idx = tid; idx < 2 * 3 * 136; idx += 256) {
        int keyp = idx % 136;
        int r = idx / 136;
        int row = r % 3, br2 = r / 3;
        s_v[br2][(13 + row) * 136 + keyp] = (row == 0) ? (unsigned short)0x3F80 : (unsigned short)0;
    }

    bf16x8 b1 = {0, 0, 0, 0, 0, 0, 0, 0};
    if (g < 2)
        b1 = *(const bf16x8*)(qT + ((size_t)b * N + n0 + qg * 16 + l15) * 16 + 8 * g);

    f32x4 zacc = {0.f, 0.f, 0.f, 0.f};

    for (int cc = 0; cc < 8; ++cc) {
        __syncthreads();
        for (int idx = tid; idx < 512; idx += 256) {
            int br2 = idx >> 8, rem = idx & 255;
            int row = rem >> 1, part = rem & 1;
            const unsigned short* src = (br2 ? kmT : khT)
                + ((size_t)b * N + cc * 128 + row) * 16 + part * 8;
            *(uint4*)&s_k[br2][row * 24 + part * 8] = *(const uint4*)src;
        }
        for (int idx = tid; idx < 416; idx += 256) {
            int br2 = idx / 208, rem = idx % 208;
            int d = rem >> 4, part = rem & 15;
            const unsigned short* src = (br2 ? vm : vh)
                + bbN + (size_t)d * N + cc * 128 + part * 8;
            *(uint4*)&s_v[br2][d * 136 + part * 8] = *(const uint4*)src;
        }
        __syncthreads();

#pragma unroll
        for (int u = 0; u < 4; ++u) {
            bf16x8 a0 = {0, 0, 0, 0, 0, 0, 0, 0}, a1v = {0, 0, 0, 0, 0, 0, 0, 0};
            if (g < 2) {
                const int rbase = 32 * u + 8 * (l15 >> 2) + (l15 & 3);
                a0  = *(const bf16x8*)&s_k[br][(rbase)     * 24 + 8 * g];
                a1v = *(const bf16x8*)&s_k[br][(rbase + 4) * 24 + 8 * g];
            }
            f32x4 d0 = {0.f, 0.f, 0.f, 0.f}, d1 = {0.f, 0.f, 0.f, 0.f};
            d0 = __builtin_amdgcn_mfma_f32_16x16x32_bf16(a0,  b1, d0, 0, 0, 0);
            d1 = __builtin_amdgcn_mfma_f32_16x16x32_bf16(a1v, b1, d1, 0, 0, 0);

            float e0[4], e1[4];
#pragma unroll
            for (int r = 0; r < 4; ++r) { e0[r] = __expf(d0[r]); e1[r] = __expf(d1[r]); }

            union { int4 iv; bf16x8 v; } u2;
            u2.iv.x = (int)pk2bf(e0[0], e0[1]);
            u2.iv.y = (int)pk2bf(e0[2], e0[3]);
            u2.iv.z = (int)pk2bf(e1[0], e1[1]);
            u2.iv.w = (int)pk2bf(e1[2], e1[3]);

            bf16x8 a2 = *(const bf16x8*)&s_v[br][l15 * 136 + 32 * u + 8 * g];
            zacc = __builtin_amdgcn_mfma_f32_16x16x32_bf16(a2, u2.v, zacc, 0, 0, 0);
        }
    }

    const float den = __shfl(zacc[1], 48 + l15, 64);
    const float rd = 1.f / den;

    float* zs = br ? s_zm : s_zh;
    const int q = qg * 16 + l15;
#pragma unroll
    for (int r = 0; r < 4; ++r) {
        int d = 4 * g + r;
        if (d < 13) zs[d * 33 + q] = zacc[r] * rd;
    }
    __syncthreads();

    for (int idx = tid; idx < 416; idx += 256) {
        int d = idx >> 5, p = idx & 31;
        float a = 0.f;
#pragma unroll
        for (int ci = 0; ci < 13; ++ci)
            a += s_wz[d * 26 + ci] * s_zh[ci * 33 + p]
               + s_wz[d * 26 + 13 + ci] * s_zm[ci * 33 + p];
        s_zc[d * 33 + p] = a;
    }
    __syncthreads();

    for (int idx = tid; idx < 416; idx += 256) {
        int d = idx >> 5, p = idx & 31;
        float mo = 0.f, mg = 0.f, mi = 0.f;
#pragma unroll
        for (int ci = 0; ci < 13; ++ci) {
            float zc = s_zc[ci * 33 + p];
            mo += s_wm[d * 26 + ci] * zc;
            mg += s_wm[(13 + d) * 26 + ci] * zc;
            mi += s_wm[(26 + d) * 26 + ci] * zc;
        }
#pragma unroll
        for (int ci = 0; ci < 13; ++ci) {
            float hc = s_hf[ci * 33 + p];
            mo += s_wm[d * 26 + 13 + ci] * hc;
            mg += s_wm[(13 + d) * 26 + 13 + ci] * hc;
            mi += s_wm[(26 + d) * 26 + 13 + ci] * hc;
        }
        mi = sigmoidf_(mi);
        const size_t gi = bbN + (size_t)d * N + n0 + p;
        float mn = (1.f - mi) * m[gi] + mi * tanhf_(mg);
        m[gi] = mn;
        h[gi] = sigmoidf_(mo) * mn;
    }
}

// ---------------------------------------------------------------- final 1x1 conv + log_softmax
__global__ __launch_bounds__(256) void k_final(
    const float* __restrict__ c, const float* __restrict__ Wf,
    const float* __restrict__ bf, float* __restrict__ out)
{
    const int i = blockIdx.x * 256 + threadIdx.x;
    const int b = i >> 10, pix = i & 1023;
    const size_t base = (size_t)b * D * N + pix;
    float cv[13];
#pragma unroll
    for (int d = 0; d < 13; ++d) cv[d] = c[base + (size_t)d * N];
    float lg[8]; float mx = -1e30f;
#pragma unroll
    for (int k = 0; k < 8; ++k) {
        float a = bf[k];
#pragma unroll
        for (int d = 0; d < 13; ++d) a += Wf[k * 13 + d] * cv[d];
        lg[k] = a; mx = fmaxf(mx, a);
    }
    float s = 0.f;
#pragma unroll
    for (int k = 0; k < 8; ++k) s += __expf(lg[k] - mx);
    float lse = mx + logf(s);
    const size_t ob = (size_t)b * 8 * N + pix;
#pragma unroll
    for (int k = 0; k < 8; ++k) out[ob + (size_t)k * N] = lg[k] - lse;
}

// ---------------------------------------------------------------- host launcher
extern "C" void kernel_launch(void* const* d_in, const int* in_sizes, int n_in,
                              void* d_out, int out_size, void* d_ws, size_t ws_size,
                              hipStream_t stream) {
    const float* x1  = (const float*)d_in[0];
    const float* Wg  = (const float*)d_in[1];
    const float* Wq  = (const float*)d_in[2];
    const float* Wkh = (const float*)d_in[3];
    const float* Wvh = (const float*)d_in[4];
    const float* Wkm = (const float*)d_in[5];
    const float* Wvm = (const float*)d_in[6];
    const float* Wz  = (const float*)d_in[7];
    const float* Wm  = (const float*)d_in[8];
    const float* Wf  = (const float*)d_in[9];
    const float* bf  = (const float*)d_in[10];

    float* ws    = (float*)d_ws;
    float* c     = ws;
    float* h     = ws + (size_t)SZ;
    float* m     = ws + (size_t)2 * SZ;
    float* h_tmp = ws + (size_t)3 * SZ;

    unsigned short* bstart = (unsigned short*)(ws + (size_t)4 * SZ);
    unsigned short* qT  = bstart;                          // [B][N][16]
    unsigned short* khT = qT  + (size_t)16 * B * N;
    unsigned short* kmT = khT + (size_t)16 * B * N;
    unsigned short* vhp = kmT + (size_t)16 * B * N;        // [B][13][N]
    unsigned short* vmp = vhp + (size_t)13 * B * N;
    unsigned short* wrA = vmp + (size_t)13 * B * N;        // 4*9*64*8 bf16 A-frags

    k_zero<<<(3 * SZ + 255) / 256, 256, 0, stream>>>(ws, 3 * SZ);
    k_wprep<<<72, 256, 0, stream>>>(Wg, wrA);

    for (int t = 0; t < T; ++t) {
        k_cp<<<dim3(16, 32), 256, 0, stream>>>(x1, wrA, h, c, m, h_tmp,
                                               qT, khT, kmT, vhp, vmp,
                                               Wq, Wkh, Wvh, Wkm, Wvm, t);
        k_attn<<<dim3(32, 32), 256, 0, stream>>>(qT, khT, kmT, vhp, vmp, h_tmp,
                                                 Wz, Wm, m, h);
    }
    k_final<<<(B * N) / 256, 256, 0, stream>>>(c, Wf, bf, (float*)d_out);
}

// Round 8
// 1183.972 us; speedup vs baseline: 4.3303x; 1.0295x over previous
//
#include <hip/hip_runtime.h>
#include <math.h>

// Problem constants
constexpr int B  = 32;
constexpr int T  = 24;
constexpr int D  = 13;
constexpr int N  = 1024;   // 32*32 spatial
constexpr int SZ = B * D * N;
constexpr int HPW = B * N * 16 / 2;   // hp size in floats (bf16 [B][N][16])

typedef __attribute__((ext_vector_type(8))) short bf16x8;
typedef __attribute__((ext_vector_type(4))) float f32x4;

__device__ __forceinline__ float sigmoidf_(float x) { return 1.f / (1.f + __expf(-x)); }
__device__ __forceinline__ float tanhf_(float x) {
    float e = __expf(2.f * x);
    return 1.f - 2.f / (e + 1.f);
}

__device__ __forceinline__ unsigned short f2bf(float f) {
    unsigned u = __float_as_uint(f);
    u += 0x8000u;
    return (unsigned short)(u >> 16);
}
__device__ __forceinline__ unsigned pk2bf(float lo, float hi) {
    unsigned a = __float_as_uint(lo) + 0x8000u;
    unsigned b = __float_as_uint(hi) + 0x8000u;
    return __builtin_amdgcn_perm(b, a, 0x07060302u);
}

// ---------------------------------------------------------------- zero init
__global__ void k_zero(float* __restrict__ p, int n) {
    int i = blockIdx.x * 256 + threadIdx.x;
    if (i < n) p[i] = 0.f;
}

// ---------------------------------------------------------------- x1 -> packed bf16 [b][t][pix][16] (one-time)
__global__ __launch_bounds__(256) void k_xprep(const float* __restrict__ x1,
                                               unsigned short* __restrict__ x1p) {
    int i = blockIdx.x * 256 + threadIdx.x;      // (b*T+t)*N + pix, < B*T*N exactly
    int pix = i & 1023, bt = i >> 10;
    const float* src = x1 + (size_t)bt * D * N + pix;
    unsigned short tmp[16];
#pragma unroll
    for (int d = 0; d < 13; ++d) tmp[d] = f2bf(src[(size_t)d * N]);
    tmp[13] = tmp[14] = tmp[15] = 0;
    uint4* dst = (uint4*)(x1p + (size_t)i * 16);
    dst[0] = ((const uint4*)tmp)[0];
    dst[1] = ((const uint4*)tmp)[1];
}

// ---------------------------------------------------------------- conv weights -> MFMA A-fragment layout (bf16)
// k map: 0..12 -> x ci=k, 13..15 -> 0, 16..28 -> h ci=k-3, 29..31 -> 0.
__global__ void k_wprep(const float* __restrict__ Wg, unsigned short* __restrict__ wrA) {
    int i = blockIdx.x * 256 + threadIdx.x;
    if (i >= 4 * 9 * 64 * 8) return;
    int j = i & 7; int r = i >> 3;
    int lane = r & 63; r >>= 6;
    int tap = r % 9; int ct = r / 9;
    int m = lane & 15, g = lane >> 4;
    int k = g * 8 + j;
    int co = ct * 16 + m;
    int ci = -1;
    if (k < 13) ci = k;
    else if (k >= 16 && k < 29) ci = k - 3;
    unsigned short v = 0;
    if (co < 52 && ci >= 0) v = f2bf(Wg[(co * 26 + ci) * 9 + tap]);
    wrA[i] = v;
}

// ---------------------------------------------------------------- fused MFMA conv + LSTM pointwise + Q/K/V projections
// grid (16 row-tiles, 32 batch), block 256 = 4 waves; tile = 2 rows (64 px).
// Inputs pre-packed bf16 (x1p, hp) -> staging is 4 coalesced dwordx4/site.
// c/m prefetched at entry. q packed with log2e folded in (exp2 softmax).
__global__ __launch_bounds__(256) void k_cp(
    const unsigned short* __restrict__ x1p, const unsigned short* __restrict__ wrA,
    const unsigned short* __restrict__ hp, float* __restrict__ c, const float* __restrict__ m_in,
    float* __restrict__ h_tmp,
    unsigned short* __restrict__ qT, unsigned short* __restrict__ khT,
    unsigned short* __restrict__ kmT, unsigned short* __restrict__ vh,
    unsigned short* __restrict__ vm,
    const float* __restrict__ Wq, const float* __restrict__ Wkh, const float* __restrict__ Wvh,
    const float* __restrict__ Wkm, const float* __restrict__ Wvm, int t)
{
    __shared__ __align__(16) unsigned short s_in[136 * 32];  // [site=row*34+col][ch32] bf16
    __shared__ float s_g[52 * 65];
    __shared__ float s_ht[13][64];
    __shared__ float s_mv[13][64];

    const int tile = blockIdx.x, b = blockIdx.y;
    const int tid = threadIdx.x;
    const int w = __builtin_amdgcn_readfirstlane(tid >> 6);
    const int lane = tid & 63;
    const int g = lane >> 4, l15 = lane & 15;
    const int y = tile * 2 + (lane >> 5), x = lane & 31;
    const int pix = y * 32 + x;
    const size_t bb = (size_t)b * D * N;

    // prefetch c, m for the pointwise phase (addresses known at entry)
    float cpre[4], mpre[4];
#pragma unroll
    for (int i2 = 0; i2 < 4; ++i2) {
        int dd = w + 4 * i2;
        if (dd < 13) {
            cpre[i2] = c[bb + (size_t)dd * N + pix];
            mpre[i2] = m_in[bb + (size_t)dd * N + pix];
        } else { cpre[i2] = 0.f; mpre[i2] = 0.f; }
    }

    // preload this wave's 9 A-fragments (co-tile = w)
    bf16x8 af[9];
#pragma unroll
    for (int tap = 0; tap < 9; ++tap)
        af[tap] = *(const bf16x8*)&wrA[(((size_t)w * 9 + tap) * 64 + lane) * 8];

    // stage input tile: 4 rows (y0-1..y0+2) x 34 cols, packed bf16 vec loads
    if (tid < 136) {
        int row = tid / 34, col = tid % 34;
        int gy = tile * 2 - 1 + row, gx = col - 1;
        bool ok = ((unsigned)gy < 32u) && ((unsigned)gx < 32u);
        uint4 z = {0, 0, 0, 0};
        uint4 a0 = z, a1 = z, b0 = z, b1 = z;
        if (ok) {
            const int off = gy * 32 + gx;
            const uint4* xs = (const uint4*)(x1p + (((size_t)b * T + t) * N + off) * 16);
            a0 = xs[0]; a1 = xs[1];
            const uint4* hs = (const uint4*)(hp + ((size_t)b * N + off) * 16);
            b0 = hs[0]; b1 = hs[1];
        }
        uint4* dst = (uint4*)&s_in[tid * 32];
        dst[0] = a0; dst[1] = a1; dst[2] = b0; dst[3] = b1;
    }
    __syncthreads();

    // ---- MFMA conv: 4 px-tiles x 9 taps
    f32x4 acc[4];
#pragma unroll
    for (int pt = 0; pt < 4; ++pt) acc[pt] = f32x4{0.f, 0.f, 0.f, 0.f};
#pragma unroll
    for (int pt = 0; pt < 4; ++pt) {
        const int px = pt * 16 + l15;
        const int r0 = px >> 5, c0 = px & 31;
#pragma unroll
        for (int tap = 0; tap < 9; ++tap) {
            const int srow = r0 + tap / 3, scol = c0 + tap % 3;
            bf16x8 bfr = *(const bf16x8*)&s_in[(srow * 34 + scol) * 32 + 8 * g];
            acc[pt] = __builtin_amdgcn_mfma_f32_16x16x32_bf16(af[tap], bfr, acc[pt], 0, 0, 0);
        }
    }
#pragma unroll
    for (int pt = 0; pt < 4; ++pt) {
#pragma unroll
        for (int rr = 0; rr < 4; ++rr) {
            const int co = w * 16 + 4 * g + rr;
            if (co < 52) s_g[co * 65 + pt * 16 + l15] = acc[pt][rr];
        }
    }
    __syncthreads();

    // ---- LSTM pointwise (prefetched c/m)
#pragma unroll
    for (int i2 = 0; i2 < 4; ++i2) {
        int dd = w + 4 * i2;
        if (dd < 13) {
            float ig = sigmoidf_(s_g[dd * 65 + lane]);
            float fg = sigmoidf_(s_g[(13 + dd) * 65 + lane]);
            float gg = tanhf_(s_g[(26 + dd) * 65 + lane]);
            float og = sigmoidf_(s_g[(39 + dd) * 65 + lane]);
            const size_t gi = bb + (size_t)dd * N + pix;
            float cn = fg * cpre[i2] + ig * gg;
            c[gi] = cn;
            float hv = og * tanhf_(cn);
            h_tmp[gi] = hv;
            s_ht[dd][lane] = hv;
            s_mv[dd][lane] = mpre[i2];
        }
    }
    __syncthreads();

    // ---- projections (weights wave-uniform -> s_load)
    const size_t ro = ((size_t)b * N + pix) * 16;
    if (w == 0) {               // q -> qT (scaled by log2e for exp2 softmax)
        float htv[13];
#pragma unroll
        for (int j = 0; j < 13; ++j) htv[j] = s_ht[j][lane];
        float o[13];
#pragma unroll
        for (int d = 0; d < 13; ++d) {
            float a = 0.f;
#pragma unroll
            for (int j = 0; j < 13; ++j) a = fmaf(Wq[d * 13 + j], htv[j], a);
            o[d] = a * 1.44269504089f;
        }
        uint4 w0, w1;
        w0.x = pk2bf(o[0], o[1]);  w0.y = pk2bf(o[2], o[3]);
        w0.z = pk2bf(o[4], o[5]);  w0.w = pk2bf(o[6], o[7]);
        w1.x = pk2bf(o[8], o[9]);  w1.y = pk2bf(o[10], o[11]);
        w1.z = pk2bf(o[12], 0.f);  w1.w = 0u;
        ((uint4*)(qT + ro))[0] = w0; ((uint4*)(qT + ro))[1] = w1;
    } else if (w == 1) {        // kh -> khT, vh
        float htv[13];
#pragma unroll
        for (int j = 0; j < 13; ++j) htv[j] = s_ht[j][lane];
        float o[13];
#pragma unroll
        for (int d = 0; d < 13; ++d) {
            float a = 0.f;
#pragma unroll
            for (int j = 0; j < 13; ++j) a = fmaf(Wkh[d * 13 + j], htv[j], a);
            o[d] = a;
        }
        uint4 w0, w1;
        w0.x = pk2bf(o[0], o[1]);  w0.y = pk2bf(o[2], o[3]);
        w0.z = pk2bf(o[4], o[5]);  w0.w = pk2bf(o[6], o[7]);
        w1.x = pk2bf(o[8], o[9]);  w1.y = pk2bf(o[10], o[11]);
        w1.z = pk2bf(o[12], 0.f);  w1.w = 0u;
        ((uint4*)(khT + ro))[0] = w0; ((uint4*)(khT + ro))[1] = w1;
#pragma unroll
        for (int d = 0; d < 13; ++d) {
            float a = 0.f;
#pragma unroll
            for (int j = 0; j < 13; ++j) a = fmaf(Wvh[d * 13 + j], htv[j], a);
            vh[bb + (size_t)d * N + pix] = f2bf(a);
        }
    } else if (w == 2) {        // km -> kmT, vm
        float mvv[13];
#pragma unroll
        for (int j = 0; j < 13; ++j) mvv[j] = s_mv[j][lane];
        float o[13];
#pragma unroll
        for (int d = 0; d < 13; ++d) {
            float a = 0.f;
#pragma unroll
            for (int j = 0; j < 13; ++j) a = fmaf(Wkm[d * 13 + j], mvv[j], a);
            o[d] = a;
        }
        uint4 w0, w1;
        w0.x = pk2bf(o[0], o[1]);  w0.y = pk2bf(o[2], o[3]);
        w0.z = pk2bf(o[4], o[5]);  w0.w = pk2bf(o[6], o[7]);
        w1.x = pk2bf(o[8], o[9]);  w1.y = pk2bf(o[10], o[11]);
        w1.z = pk2bf(o[12], 0.f);  w1.w = 0u;
        ((uint4*)(kmT + ro))[0] = w0; ((uint4*)(kmT + ro))[1] = w1;
#pragma unroll
        for (int d = 0; d < 13; ++d) {
            float a = 0.f;
#pragma unroll
            for (int j = 0; j < 13; ++j) a = fmaf(Wvm[d * 13 + j], mvv[j], a);
            vm[bb + (size_t)d * N + pix] = f2bf(a);
        }
    }
}

// ---------------------------------------------------------------- MFMA dual attention + fused SAM epilogue
// grid (32,32), block 256 (proven shape). 128-key chunks, single LDS buffer,
// REGISTER double-buffering: chunk cc+1 loads issued during compute of cc.
// exp2 softmax (q pre-scaled). h emitted as packed bf16 hp[pix][16].
__global__ __launch_bounds__(256) void k_attn(
    const unsigned short* __restrict__ qT, const unsigned short* __restrict__ khT,
    const unsigned short* __restrict__ kmT, const unsigned short* __restrict__ vh,
    const unsigned short* __restrict__ vm, const float* __restrict__ h_tmp,
    const float* __restrict__ Wz, const float* __restrict__ Wm,
    float* __restrict__ m, unsigned short* __restrict__ hp)
{
    __shared__ __align__(16) unsigned short s_k[2][128 * 24]; // [br][key*24 + d]
    __shared__ __align__(16) unsigned short s_v[2][16 * 136]; // [br][d*136 + key]
    __shared__ __align__(16) unsigned short s_hout[32 * 16];
    __shared__ float s_hf[13 * 33];
    __shared__ float s_zh[13 * 33], s_zm[13 * 33], s_zc[13 * 33];
    __shared__ float s_wz[13 * 26];
    __shared__ float s_wm[39 * 26];

    const int b = blockIdx.y, n0 = blockIdx.x * 32, tid = threadIdx.x;
    const int lane = tid & 63, w = tid >> 6;
    const int g = lane >> 4, l15 = lane & 15;
    const int br = w >> 1, qg = w & 1;
    const size_t bbN = (size_t)b * D * N;

    for (int idx = tid; idx < 13 * 26; idx += 256) s_wz[idx] = Wz[idx];
    for (int idx = tid; idx < 39 * 26; idx += 256) s_wm[idx] = Wm[idx];
    for (int idx = tid; idx < 13 * 32; idx += 256) {
        int d = idx >> 5, p = idx & 31;
        s_hf[d * 33 + p] = h_tmp[bbN + (size_t)d * N + n0 + p];
    }
    for (int idx = tid; idx < 512; idx += 256) s_hout[idx] = 0;
    // V pad rows: row 13 = bf16 1.0 (free denominator), rows 14/15 = 0
    for (int idx = tid; idx < 2 * 3 * 136; idx += 256) {
        int keyp = idx % 136;
        int r = idx / 136;
        int row = r % 3, br2 = r / 3;
        s_v[br2][(13 + row) * 136 + keyp] = (row == 0) ? (unsigned short)0x3F80 : (unsigned short)0;
    }

    // constant q fragment
    bf16x8 b1 = {0, 0, 0, 0, 0, 0, 0, 0};
    if (g < 2)
        b1 = *(const bf16x8*)(qT + ((size_t)b * N + n0 + qg * 16 + l15) * 16 + 8 * g);

    // staging piece assignments (register double-buffered)
    const int rowk = tid >> 1, partk = tid & 1;
    const unsigned short* kb0 = khT + ((size_t)b * N + rowk) * 16 + partk * 8;
    const unsigned short* kb1 = kmT + ((size_t)b * N + rowk) * 16 + partk * 8;
    unsigned short* sk0 = &s_k[0][rowk * 24 + partk * 8];
    unsigned short* sk1 = &s_k[1][rowk * 24 + partk * 8];
    const int brv0 = (tid >= 208) ? 1 : 0;
    const int rem0 = tid - 208 * brv0;
    const int dv0 = rem0 >> 4, pv0 = rem0 & 15;
    const unsigned short* vb0 = (brv0 ? vm : vh) + bbN + (size_t)dv0 * N + pv0 * 8;
    unsigned short* sv0 = &s_v[brv0][dv0 * 136 + pv0 * 8];
    const bool doV1 = (tid < 160);
    const int rem1 = tid + 48;                 // (tid+256)-208, br=1
    const int dv1 = rem1 >> 4, pv1 = rem1 & 15;
    const unsigned short* vb1 = vm + bbN + (size_t)dv1 * N + pv1 * 8;
    unsigned short* sv1 = &s_v[1][dv1 * 136 + pv1 * 8];

    uint4 rk0 = *(const uint4*)kb0;
    uint4 rk1 = *(const uint4*)kb1;
    uint4 rv0 = *(const uint4*)vb0;
    uint4 rv1 = doV1 ? *(const uint4*)vb1 : uint4{0, 0, 0, 0};

    f32x4 zacc = {0.f, 0.f, 0.f, 0.f};

    for (int cc = 0; cc < 8; ++cc) {
        if (cc) __syncthreads();             // prior compute done reading LDS
        *(uint4*)sk0 = rk0;
        *(uint4*)sk1 = rk1;
        *(uint4*)sv0 = rv0;
        if (doV1) *(uint4*)sv1 = rv1;
        __syncthreads();
        if (cc < 7) {                        // issue next chunk's loads now
            const size_t ko = (size_t)(cc + 1) * 128 * 16;
            const size_t vo = (size_t)(cc + 1) * 128;
            rk0 = *(const uint4*)(kb0 + ko);
            rk1 = *(const uint4*)(kb1 + ko);
            rv0 = *(const uint4*)(vb0 + vo);
            if (doV1) rv1 = *(const uint4*)(vb1 + vo);
        }
#pragma unroll
        for (int u = 0; u < 4; ++u) {
            bf16x8 a0 = {0, 0, 0, 0, 0, 0, 0, 0}, a1v = {0, 0, 0, 0, 0, 0, 0, 0};
            if (g < 2) {
                const int rbase = 32 * u + 8 * (l15 >> 2) + (l15 & 3);
                a0  = *(const bf16x8*)&s_k[br][(rbase)     * 24 + 8 * g];
                a1v = *(const bf16x8*)&s_k[br][(rbase + 4) * 24 + 8 * g];
            }
            f32x4 d0 = {0.f, 0.f, 0.f, 0.f}, d1 = {0.f, 0.f, 0.f, 0.f};
            d0 = __builtin_amdgcn_mfma_f32_16x16x32_bf16(a0,  b1, d0, 0, 0, 0);
            d1 = __builtin_amdgcn_mfma_f32_16x16x32_bf16(a1v, b1, d1, 0, 0, 0);

            float e0[4], e1[4];
#pragma unroll
            for (int r = 0; r < 4; ++r) { e0[r] = exp2f(d0[r]); e1[r] = exp2f(d1[r]); }

            union { int4 iv; bf16x8 v; } u2;
            u2.iv.x = (int)pk2bf(e0[0], e0[1]);
            u2.iv.y = (int)pk2bf(e0[2], e0[3]);
            u2.iv.z = (int)pk2bf(e1[0], e1[1]);
            u2.iv.w = (int)pk2bf(e1[2], e1[3]);

            bf16x8 a2 = *(const bf16x8*)&s_v[br][l15 * 136 + 32 * u + 8 * g];
            zacc = __builtin_amdgcn_mfma_f32_16x16x32_bf16(a2, u2.v, zacc, 0, 0, 0);
        }
    }

    // denominator = accumulator row 13 (V pad row of ones): lane 48+l15, reg 1
    const float den = __shfl(zacc[1], 48 + l15, 64);
    const float rd = 1.f / den;

    float* zs = br ? s_zm : s_zh;
    const int q = qg * 16 + l15;
#pragma unroll
    for (int r = 0; r < 4; ++r) {
        int d = 4 * g + r;
        if (d < 13) zs[d * 33 + q] = zacc[r] * rd;
    }
    __syncthreads();

    // Zc = Wz [Zh; Zm]
    for (int idx = tid; idx < 416; idx += 256) {
        int d = idx >> 5, p = idx & 31;
        float a = 0.f;
#pragma unroll
        for (int ci = 0; ci < 13; ++ci)
            a += s_wz[d * 26 + ci] * s_zh[ci * 33 + p]
               + s_wz[d * 26 + 13 + ci] * s_zm[ci * 33 + p];
        s_zc[d * 33 + p] = a;
    }
    __syncthreads();

    // comb = Wm [Zc; hf]; update m; h -> s_hout (bf16)
    for (int idx = tid; idx < 416; idx += 256) {
        int d = idx >> 5, p = idx & 31;
        float mo = 0.f, mg = 0.f, mi = 0.f;
#pragma unroll
        for (int ci = 0; ci < 13; ++ci) {
            float zc = s_zc[ci * 33 + p];
            mo += s_wm[d * 26 + ci] * zc;
            mg += s_wm[(13 + d) * 26 + ci] * zc;
            mi += s_wm[(26 + d) * 26 + ci] * zc;
        }
#pragma unroll
        for (int ci = 0; ci < 13; ++ci) {
            float hc = s_hf[ci * 33 + p];
            mo += s_wm[d * 26 + 13 + ci] * hc;
            mg += s_wm[(13 + d) * 26 + 13 + ci] * hc;
            mi += s_wm[(26 + d) * 26 + 13 + ci] * hc;
        }
        mi = sigmoidf_(mi);
        const size_t gi = bbN + (size_t)d * N + n0 + p;
        float mn = (1.f - mi) * m[gi] + mi * tanhf_(mg);
        m[gi] = mn;
        s_hout[p * 16 + d] = f2bf(sigmoidf_(mo) * mn);
    }
    __syncthreads();

    if (tid < 32) {   // pack h for this tile: hp[b][n0+tid][16]
        uint4* dst = (uint4*)(hp + ((size_t)b * N + n0 + tid) * 16);
        const uint4* srcp = (const uint4*)&s_hout[tid * 16];
        dst[0] = srcp[0]; dst[1] = srcp[1];
    }
}

// ---------------------------------------------------------------- final 1x1 conv + log_softmax
__global__ __launch_bounds__(256) void k_final(
    const float* __restrict__ c, const float* __restrict__ Wf,
    const float* __restrict__ bf, float* __restrict__ out)
{
    const int i = blockIdx.x * 256 + threadIdx.x;
    const int b = i >> 10, pix = i & 1023;
    const size_t base = (size_t)b * D * N + pix;
    float cv[13];
#pragma unroll
    for (int d = 0; d < 13; ++d) cv[d] = c[base + (size_t)d * N];
    float lg[8]; float mx = -1e30f;
#pragma unroll
    for (int k = 0; k < 8; ++k) {
        float a = bf[k];
#pragma unroll
        for (int d = 0; d < 13; ++d) a += Wf[k * 13 + d] * cv[d];
        lg[k] = a; mx = fmaxf(mx, a);
    }
    float s = 0.f;
#pragma unroll
    for (int k = 0; k < 8; ++k) s += __expf(lg[k] - mx);
    float lse = mx + logf(s);
    const size_t ob = (size_t)b * 8 * N + pix;
#pragma unroll
    for (int k = 0; k < 8; ++k) out[ob + (size_t)k * N] = lg[k] - lse;
}

// ---------------------------------------------------------------- host launcher
extern "C" void kernel_launch(void* const* d_in, const int* in_sizes, int n_in,
                              void* d_out, int out_size, void* d_ws, size_t ws_size,
                              hipStream_t stream) {
    const float* x1  = (const float*)d_in[0];
    const float* Wg  = (const float*)d_in[1];
    const float* Wq  = (const float*)d_in[2];
    const float* Wkh = (const float*)d_in[3];
    const float* Wvh = (const float*)d_in[4];
    const float* Wkm = (const float*)d_in[5];
    const float* Wvm = (const float*)d_in[6];
    const float* Wz  = (const float*)d_in[7];
    const float* Wm  = (const float*)d_in[8];
    const float* Wf  = (const float*)d_in[9];
    const float* bf  = (const float*)d_in[10];

    float* ws    = (float*)d_ws;
    float* c     = ws;
    float* m     = ws + (size_t)SZ;
    unsigned short* hp = (unsigned short*)(ws + (size_t)2 * SZ);   // [B][N][16] bf16
    float* h_tmp = ws + (size_t)2 * SZ + HPW;

    unsigned short* bstart = (unsigned short*)(ws + (size_t)3 * SZ + HPW);
    unsigned short* qT  = bstart;                          // [B][N][16]
    unsigned short* khT = qT  + (size_t)16 * B * N;
    unsigned short* kmT = khT + (size_t)16 * B * N;
    unsigned short* vhp = kmT + (size_t)16 * B * N;        // [B][13][N]
    unsigned short* vmp = vhp + (size_t)13 * B * N;
    unsigned short* x1p = vmp + (size_t)13 * B * N;        // [B][T][N][16]
    unsigned short* wrA = x1p + (size_t)16 * B * T * N;    // A-frags

    // zero c, m, hp (contiguous region)
    k_zero<<<(2 * SZ + HPW + 255) / 256, 256, 0, stream>>>(ws, 2 * SZ + HPW);
    k_wprep<<<72, 256, 0, stream>>>(Wg, wrA);
    k_xprep<<<(B * T * N) / 256, 256, 0, stream>>>(x1, x1p);

    for (int t = 0; t < T; ++t) {
        k_cp<<<dim3(16, 32), 256, 0, stream>>>(x1p, wrA, hp, c, m, h_tmp,
                                               qT, khT, kmT, vhp, vmp,
                                               Wq, Wkh, Wvh, Wkm, Wvm, t);
        k_attn<<<dim3(32, 32), 256, 0, stream>>>(qT, khT, kmT, vhp, vmp, h_tmp,
                                                 Wz, Wm, m, hp);
    }
    k_final<<<(B * N) / 256, 256, 0, stream>>>(c, Wf, bf, (float*)d_out);
}